// Round 17
// baseline (242.986 us; speedup 1.0000x reference)
//
#include <hip/hip_runtime.h>
#include <hip/hip_bf16.h>
#include <stdint.h>

// MQA: B=2, S=2048, D=1024, H=16, DH=64. Inputs f32, OUTPUT f32.
// r17: attn gets (a) double-buffered LDS staging of packed K/V tiles (4 waves
// share -> L1/L2 delivery /4), (b) balanced max tree + permlane32_swap reduces
// (serial softmax chain cut). Everything else = r16.

#define B_   2
#define S_   2048
#define D_   1024
#define H_   16
#define DH_  64
#define MTOT (B_ * S_)  // 4096
#define NSPL 4

typedef short bf16x8 __attribute__((ext_vector_type(8)));
typedef float f32x4 __attribute__((ext_vector_type(4)));
typedef float f32x16 __attribute__((ext_vector_type(16)));
typedef short short4v __attribute__((ext_vector_type(4)));
typedef unsigned uint4v __attribute__((ext_vector_type(4)));

__device__ __forceinline__ short f2bf(float f) {  // RNE f32->bf16
  unsigned u = __float_as_uint(f);
  u += 0x7FFF + ((u >> 16) & 1);
  return (short)(u >> 16);
}
__device__ __forceinline__ float bf2f(short h) {
  return __uint_as_float(((unsigned)(unsigned short)h) << 16);
}
struct bfpair { short hi, lo; };
__device__ __forceinline__ bfpair split2(float x) {
  bfpair p;
  p.hi = f2bf(x);
  p.lo = f2bf(x - bf2f(p.hi));
  return p;
}
__device__ __forceinline__ unsigned cvtpk(float lo, float hi) {
  unsigned r;
  asm("v_cvt_pk_bf16_f32 %0, %1, %2" : "=v"(r) : "v"(lo), "v"(hi));
  return r;
}
// cross-half (lane ^ 32) pair via permlane32_swap: per lane returns {x[l], x[l^32]}
__device__ __forceinline__ float2 xhalf(float x) {
  unsigned u = __float_as_uint(x);
  auto sw = __builtin_amdgcn_permlane32_swap(u, u, false, false);
  return make_float2(__uint_as_float(sw[0]), __uint_as_float(sw[1]));
}

__device__ __forceinline__ void glds16(const void* g, void* l) {
  __builtin_amdgcn_global_load_lds((const __attribute__((address_space(1))) void*)g,
                                   (__attribute__((address_space(3))) void*)l, 16, 0, 0);
}

// ---------------- f32 -> bf16 convert; hi/lo split for q,k,wq,wk only ----------------
__global__ __launch_bounds__(256) void cvt_split(
    const float* __restrict__ q, const float* __restrict__ k, const float* __restrict__ v,
    const float* __restrict__ wq, const float* __restrict__ wk, const float* __restrict__ wv,
    const float* __restrict__ wo,
    short* qhi, short* qlo, short* khi, short* klo, short* vb,
    short* wqh, short* wql, short* wkh, short* wkl, short* wvb, short* wob) {
  const int U0 = 1048576, U1 = 2097152, U2 = 3145728, U3 = 3407872,
            U4 = 3424256, U5 = 3440640, U6 = 3702784;
  for (int u = blockIdx.x * blockDim.x + threadIdx.x; u < U6; u += gridDim.x * blockDim.x) {
    const float* s; short* dh; short* dl; int r;
    if (u < U0)      { s = q;  dh = qhi; dl = qlo; r = u; }
    else if (u < U1) { s = k;  dh = khi; dl = klo; r = u - U0; }
    else if (u < U2) { s = v;  dh = vb;  dl = nullptr; r = u - U1; }
    else if (u < U3) { s = wq; dh = wqh; dl = wql; r = u - U2; }
    else if (u < U4) { s = wk; dh = wkh; dl = wkl; r = u - U3; }
    else if (u < U5) { s = wv; dh = wvb; dl = nullptr; r = u - U4; }
    else             { s = wo; dh = wob; dl = nullptr; r = u - U5; }
    float4 x = *(const float4*)(s + (size_t)r * 4);
    bfpair p0 = split2(x.x), p1 = split2(x.y), p2 = split2(x.z), p3 = split2(x.w);
    short4v yh, yl;
    yh.x = p0.hi; yh.y = p1.hi; yh.z = p2.hi; yh.w = p3.hi;
    yl.x = p0.lo; yl.y = p1.lo; yl.z = p2.lo; yl.w = p3.lo;
    *(short4v*)(dh + (size_t)r * 4) = yh;
    if (dl) *(short4v*)(dl + (size_t)r * 4) = yl;
  }
}

// ---------------- GEMM  C = (Ah+Al) * (Bh+Bl)^T, f32 acc ----------------
// MODE 0: split pair row-major. MODE 3: f32 row-major.
// MODE 4: K-fragment-packed split pair  PK[tok>>5][dh>>4][(tok&31)+32*((dh>>3)&1)][dh&7]
// MODE 5: V-fragment-packed single bf16 PV[tok>>5][dh>>5][(tok>>4)&1][(dh&31)+32*((tok>>3)&1)][tok&7]
template <int NPROD, int MODE>
__global__ __launch_bounds__(256) void gemm3(
    const short* __restrict__ Ah, const short* __restrict__ Al,
    const short* __restrict__ Bh, const short* __restrict__ Bl,
    short* __restrict__ Ch, short* __restrict__ Cl, float* __restrict__ Cf,
    int K, int lda, int ldb, int ldc, float alpha) {
  __shared__ alignas(16) short Ash[4096], Asl[4096], Bsh[4096], Bsl[4096];
  const int tid = threadIdx.x;
  const int lane = tid & 63, w = tid >> 6;
  const int c = lane & 15, g = lane >> 4;
  const int wm = w >> 1, wn = w & 1;
  const int bm = blockIdx.x * 64, bn = blockIdx.y * 64;
  const int sr = lane >> 3;
  const int scs = ((lane & 7) ^ sr) * 8;

  f32x4 acc[2][2] = {};
  for (int k0 = 0; k0 < K; k0 += 64) {
    glds16(Ah + (size_t)(bm + w * 8 + sr) * lda + k0 + scs,      Ash + w * 512);
    glds16(Ah + (size_t)(bm + 32 + w * 8 + sr) * lda + k0 + scs, Ash + 2048 + w * 512);
    glds16(Bh + (size_t)(bn + w * 8 + sr) * ldb + k0 + scs,      Bsh + w * 512);
    glds16(Bh + (size_t)(bn + 32 + w * 8 + sr) * ldb + k0 + scs, Bsh + 2048 + w * 512);
    if constexpr (NPROD == 3) {
      glds16(Al + (size_t)(bm + w * 8 + sr) * lda + k0 + scs,      Asl + w * 512);
      glds16(Al + (size_t)(bm + 32 + w * 8 + sr) * lda + k0 + scs, Asl + 2048 + w * 512);
      glds16(Bl + (size_t)(bn + w * 8 + sr) * ldb + k0 + scs,      Bsl + w * 512);
      glds16(Bl + (size_t)(bn + 32 + w * 8 + sr) * ldb + k0 + scs, Bsl + 2048 + w * 512);
    }
    __syncthreads();
#pragma unroll
    for (int kk = 0; kk < 2; ++kk) {
      bf16x8 ah[2], bh[2], al[2], bl[2];
#pragma unroll
      for (int mt = 0; mt < 2; ++mt) {
        int row = wm * 32 + mt * 16 + c;
        int so = row * 64 + (((kk * 4 + g) ^ (row & 7)) * 8);
        ah[mt] = *(const bf16x8*)(Ash + so);
        if constexpr (NPROD == 3) al[mt] = *(const bf16x8*)(Asl + so);
      }
#pragma unroll
      for (int nt = 0; nt < 2; ++nt) {
        int row = wn * 32 + nt * 16 + c;
        int so = row * 64 + (((kk * 4 + g) ^ (row & 7)) * 8);
        bh[nt] = *(const bf16x8*)(Bsh + so);
        if constexpr (NPROD == 3) bl[nt] = *(const bf16x8*)(Bsl + so);
      }
#pragma unroll
      for (int mt = 0; mt < 2; ++mt)
#pragma unroll
        for (int nt = 0; nt < 2; ++nt) {
          acc[mt][nt] = __builtin_amdgcn_mfma_f32_16x16x32_bf16(ah[mt], bh[nt], acc[mt][nt], 0, 0, 0);
          if constexpr (NPROD == 3) {
            acc[mt][nt] = __builtin_amdgcn_mfma_f32_16x16x32_bf16(ah[mt], bl[nt], acc[mt][nt], 0, 0, 0);
            acc[mt][nt] = __builtin_amdgcn_mfma_f32_16x16x32_bf16(al[mt], bh[nt], acc[mt][nt], 0, 0, 0);
          }
        }
    }
    __syncthreads();
  }
#pragma unroll
  for (int mt = 0; mt < 2; ++mt) {
#pragma unroll
    for (int nt = 0; nt < 2; ++nt) {
#pragma unroll
      for (int r = 0; r < 4; ++r) {
        int m = bm + wm * 32 + mt * 16 + g * 4 + r;   // row (token)
        int n = bn + wn * 32 + nt * 16 + c;           // col (dh / N)
        float val = acc[mt][nt][r] * alpha;
        if constexpr (MODE == 0) {
          bfpair pr = split2(val);
          Ch[(size_t)m * ldc + n] = pr.hi;
          Cl[(size_t)m * ldc + n] = pr.lo;
        } else if constexpr (MODE == 3) {
          Cf[(size_t)m * ldc + n] = val;
        } else if constexpr (MODE == 4) {
          size_t off = (((size_t)(m >> 5) * 4 + (n >> 4)) * 64 +
                        ((m & 31) + 32 * ((n >> 3) & 1))) * 8 + (n & 7);
          bfpair pr = split2(val);
          Ch[off] = pr.hi;
          Cl[off] = pr.lo;
        } else {  // MODE 5
          size_t off = ((((size_t)(m >> 5) * 2 + (n >> 5)) * 2 + ((m >> 4) & 1)) * 64 +
                        ((n & 31) + 32 * ((m >> 3) & 1))) * 8 + (m & 7);
          Ch[off] = f2bf(val);
        }
      }
    }
  }
}

// ---------------- flash MQA attention v10: LDS-staged K/V, fast reduces ----------
// grid (S/128, H, B*NSPL), 256 thr = 4 waves; wave w owns 32 q-rows; kv range = S/4.
// Per iter: all 4 waves share one 12KB packed K/V tile staged via global_load_lds
// (double-buffered); next tile prefetch issued before compute; 1 barrier/iter.
__global__ __launch_bounds__(256) void mqa_attn(
    const short* __restrict__ qph, const short* __restrict__ qpl,
    const short* __restrict__ pkh, const short* __restrict__ pkl,
    const short* __restrict__ pv, short* __restrict__ pO, float* __restrict__ pML) {
  __shared__ alignas(16) short Kls[2][3][2048];  // [buf][khi|klo|v][4KB] = 24KB
  const int tid = threadIdx.x;
  const int lane = tid & 63, w = tid >> 6;
  const int j = lane & 31, b5 = lane >> 5;
  const int qt = blockIdx.x, h = blockIdx.y;
  const int b = blockIdx.z >> 2, sp = blockIdx.z & 3;
  const int q0 = qt * 128 + w * 32;
  const int kvbeg = sp * (S_ / NSPL), kvend = kvbeg + S_ / NSPL;

  const size_t qbase = (size_t)(b * S_ + q0 + j) * D_ + h * DH_ + b5 * 8;
  bf16x8 qh[4], ql[4];
#pragma unroll
  for (int m = 0; m < 4; ++m) {
    qh[m] = *(const bf16x8*)(qph + qbase + m * 16);
    ql[m] = *(const bf16x8*)(qpl + qbase + m * 16);
  }

  // stage one packed 32-kv tile (12KB) into Kls[buf]; wave w covers calls w, w+4, w+8
  auto stage = [&](int buf, size_t tg) {
#pragma unroll
    for (int i = 0; i < 3; ++i) {
      int cc = w + 4 * i;
      int part = cc >> 2, qq = cc & 3;
      const short* src = (part == 0 ? pkh : (part == 1 ? pkl : pv));
      glds16(src + tg * 2048 + qq * 512 + lane * 8, &Kls[buf][part][qq * 512]);
    }
  };

  float mrow = -1.0e30f, lrow = 0.f;
  f32x16 o0 = {}, o1 = {};

  const size_t tg0 = (size_t)((b * S_ + kvbeg) >> 5);
  stage(0, tg0);
  __syncthreads();
  int cur = 0;

  for (int kv0 = kvbeg; kv0 < kvend; kv0 += 32) {
    if (kv0 + 32 < kvend) stage(cur ^ 1, tg0 + ((kv0 - kvbeg) >> 5) + 1);
    // ---- K fragments from LDS ----
    bf16x8 kh[4], kl[4];
#pragma unroll
    for (int m = 0; m < 4; ++m) {
      kh[m] = *(const bf16x8*)(&Kls[cur][0][m * 512 + lane * 8]);
      kl[m] = *(const bf16x8*)(&Kls[cur][1][m * 512 + lane * 8]);
    }
    // ---- scores: 12 MFMAs chained into ONE accumulator ----
    f32x16 s = {};
#pragma unroll
    for (int m = 0; m < 4; ++m)
      s = __builtin_amdgcn_mfma_f32_32x32x16_bf16(kh[m], qh[m], s, 0, 0, 0);
#pragma unroll
    for (int m = 0; m < 4; ++m)
      s = __builtin_amdgcn_mfma_f32_32x32x16_bf16(kl[m], qh[m], s, 0, 0, 0);
#pragma unroll
    for (int m = 0; m < 4; ++m)
      s = __builtin_amdgcn_mfma_f32_32x32x16_bf16(kh[m], ql[m], s, 0, 0, 0);
    // ---- softmax: balanced max tree (depth 4) + permlane cross-half ----
    float a0 = fmaxf(s[0], s[1]), a1 = fmaxf(s[2], s[3]),
          a2 = fmaxf(s[4], s[5]), a3 = fmaxf(s[6], s[7]),
          a4 = fmaxf(s[8], s[9]), a5 = fmaxf(s[10], s[11]),
          a6 = fmaxf(s[12], s[13]), a7 = fmaxf(s[14], s[15]);
    float b0 = fmaxf(a0, a1), b1 = fmaxf(a2, a3), b2 = fmaxf(a4, a5), b3 = fmaxf(a6, a7);
    float mx = fmaxf(fmaxf(b0, b1), fmaxf(b2, b3));
    float2 xh = xhalf(mx);
    mx = fmaxf(xh.x, xh.y);
    if (!__all(mx - mrow <= 8.0f)) {
      float mn = fmaxf(mrow, mx);
      float scale = exp2f(mrow - mn);
      mrow = mn;
      lrow *= scale;
      o0 *= scale;
      o1 *= scale;
    }
    float p[16];
#pragma unroll
    for (int r = 0; r < 16; ++r) p[r] = exp2f(s[r] - mrow);
    float rs = (((p[0] + p[1]) + (p[2] + p[3])) + ((p[4] + p[5]) + (p[6] + p[7]))) +
               (((p[8] + p[9]) + (p[10] + p[11])) + ((p[12] + p[13]) + (p[14] + p[15])));
    float2 rh = xhalf(rs);
    rs = rh.x + rh.y;
    lrow += rs;
    // ---- P^T fragments via cvt_pk + permlane32_swap ----
    auto r0 = __builtin_amdgcn_permlane32_swap(cvtpk(p[0], p[1]),   cvtpk(p[4], p[5]),   false, false);
    auto r1 = __builtin_amdgcn_permlane32_swap(cvtpk(p[2], p[3]),   cvtpk(p[6], p[7]),   false, false);
    auto r2 = __builtin_amdgcn_permlane32_swap(cvtpk(p[8], p[9]),   cvtpk(p[12], p[13]), false, false);
    auto r3 = __builtin_amdgcn_permlane32_swap(cvtpk(p[10], p[11]), cvtpk(p[14], p[15]), false, false);
    union { uint4v u; bf16x8 v; } pa0, pa1;
    pa0.u = (uint4v){r0[0], r1[0], r0[1], r1[1]};  // kv 0..15 (per b5 half)
    pa1.u = (uint4v){r2[0], r3[0], r2[1], r3[1]};  // kv 16..31
    // ---- O^T += V^T x P^T : V from LDS ----
    bf16x8 va00 = *(const bf16x8*)(&Kls[cur][2][lane * 8]);
    bf16x8 va01 = *(const bf16x8*)(&Kls[cur][2][512 + lane * 8]);
    bf16x8 va10 = *(const bf16x8*)(&Kls[cur][2][1024 + lane * 8]);
    bf16x8 va11 = *(const bf16x8*)(&Kls[cur][2][1536 + lane * 8]);
    o0 = __builtin_amdgcn_mfma_f32_32x32x16_bf16(va00, pa0.v, o0, 0, 0, 0);
    o0 = __builtin_amdgcn_mfma_f32_32x32x16_bf16(va01, pa1.v, o0, 0, 0, 0);
    o1 = __builtin_amdgcn_mfma_f32_32x32x16_bf16(va10, pa0.v, o1, 0, 0, 0);
    o1 = __builtin_amdgcn_mfma_f32_32x32x16_bf16(va11, pa1.v, o1, 0, 0, 0);
    __syncthreads();
    cur ^= 1;
  }
  const size_t tok = (size_t)(b * S_ + q0 + j);
  const size_t obase = ((size_t)sp * MTOT + tok) * D_ + h * DH_;
#pragma unroll
  for (int r = 0; r < 16; ++r) {
    int dh0 = (r & 3) + 8 * (r >> 2) + 4 * b5;
    pO[obase + dh0] = f2bf(o0[r]);
    pO[obase + 32 + dh0] = f2bf(o1[r]);
  }
  if (b5 == 0) {
    size_t mb = (((size_t)sp * MTOT + tok) * H_ + h) * 2;
    pML[mb] = mrow;
    pML[mb + 1] = lrow;
  }
}

// ---------------- merge NSPL KV-split partials -> single bf16 ao ----------------
__global__ __launch_bounds__(256) void attn_merge(
    const short* __restrict__ pO, const float* __restrict__ pML,
    short* __restrict__ ao) {
  int qd = blockIdx.x * 256 + threadIdx.x;
  size_t idx = (size_t)qd * 4;
  int tok = (int)(idx >> 10);
  int h = (int)((idx >> 6) & 15);
  float ms[NSPL], ls[NSPL], mm = -1.0e30f;
#pragma unroll
  for (int s = 0; s < NSPL; ++s) {
    size_t mb = (((size_t)s * MTOT + tok) * H_ + h) * 2;
    ms[s] = pML[mb];
    ls[s] = pML[mb + 1];
    mm = fmaxf(mm, ms[s]);
  }
  float num[4] = {}, den = 0.f;
#pragma unroll
  for (int s = 0; s < NSPL; ++s) {
    float e = exp2f(ms[s] - mm);
    den += ls[s] * e;
    short4v o4 = *(const short4v*)(pO + (size_t)s * MTOT * D_ + idx);
    num[0] += bf2f(o4.x) * e;
    num[1] += bf2f(o4.y) * e;
    num[2] += bf2f(o4.z) * e;
    num[3] += bf2f(o4.w) * e;
  }
  float inv = 1.0f / den;
  short4v y;
  y.x = f2bf(num[0] * inv);
  y.y = f2bf(num[1] * inv);
  y.z = f2bf(num[2] * inv);
  y.w = f2bf(num[3] * inv);
  *(short4v*)(ao + idx) = y;
}

// ---------------- launch ----------------
extern "C" void kernel_launch(void* const* d_in, const int* in_sizes, int n_in,
                              void* d_out, int out_size, void* d_ws, size_t ws_size,
                              hipStream_t stream) {
  const float* q  = (const float*)d_in[0];
  const float* k  = (const float*)d_in[1];
  const float* v  = (const float*)d_in[2];
  const float* wq = (const float*)d_in[3];
  const float* wk = (const float*)d_in[4];
  const float* wv = (const float*)d_in[5];
  const float* wo = (const float*)d_in[6];

  short* p = (short*)d_ws;
  short* qhi = p; p += 4194304;   // dead after Q-proj -> pO splits 0,1
  short* qlo = p; p += 4194304;
  short* khi = p; p += 4194304;   // dead after K-proj -> pO splits 2,3
  short* klo = p; p += 4194304;
  short* vb  = p; p += 4194304;   // dead after V-proj -> pML
  short* wqh = p; p += 1048576;
  short* wql = p; p += 1048576;
  short* wkh = p; p += 65536;
  short* wkl = p; p += 65536;
  short* wvb = p; p += 65536;
  short* wob = p; p += 1048576;
  short* qph = p; p += 4194304;   // dead after attn -> ao
  short* qpl = p; p += 4194304;
  short* pkh = p; p += 524288;    // packed K hi [128 tiles][4][64][8]
  short* pkl = p; p += 524288;    // packed K lo
  short* pv  = p; p += 524288;    // packed V^T [128 tiles][2][2][64][8]
  short* pO  = qhi;               // [NSPL][4096][1024] bf16 = 33.6 MB
  float* pML = (float*)vb;        // [NSPL][4096][16][2] f32 = 2 MB
  short* ao  = qph;               // merge runs after attn reads qph/qpl

  cvt_split<<<dim3(2048), dim3(256), 0, stream>>>(q, k, v, wq, wk, wv, wo,
      qhi, qlo, khi, klo, vb, wqh, wql, wkh, wkl, wvb, wob);
  // qp = q @ wq^T * (0.125 * log2e)  -> exp2-domain scores
  gemm3<3, 0><<<dim3(64, 16), dim3(256), 0, stream>>>(qhi, qlo, wqh, wql, qph, qpl,
      nullptr, 1024, 1024, 1024, 1024, 0.125f * 1.44269504f);
  // kp -> packed fragment layout (split)
  gemm3<3, 4><<<dim3(64, 1), dim3(256), 0, stream>>>(khi, klo, wkh, wkl, pkh, pkl,
      nullptr, 1024, 1024, 1024, 64, 1.0f);
  // vp -> packed V^T fragment layout
  gemm3<1, 5><<<dim3(64, 1), dim3(256), 0, stream>>>(vb, nullptr, wvb, nullptr, pv,
      nullptr, nullptr, 1024, 1024, 1024, 64, 1.0f);
  mqa_attn<<<dim3(S_ / 128, 16, B_ * NSPL), dim3(256), 0, stream>>>(
      qph, qpl, pkh, pkl, pv, pO, pML);
  attn_merge<<<dim3(MTOT * D_ / 4 / 256), dim3(256), 0, stream>>>(pO, pML, ao);
  // d_out(f32) = ao @ wo^T  (single bf16 — post-softmax path tolerates it)
  gemm3<1, 3><<<dim3(64, 16), dim3(256), 0, stream>>>(ao, nullptr, wob, nullptr,
      nullptr, nullptr, (float*)d_out, 1024, 1024, 1024, 1024, 1.0f);
}

// Round 18
// 217.207 us; speedup vs baseline: 1.1187x; 1.1187x over previous
//
#include <hip/hip_runtime.h>
#include <hip/hip_bf16.h>
#include <stdint.h>

// MQA: B=2, S=2048, D=1024, H=16, DH=64. Inputs f32, OUTPUT f32.
// r18: attn reverted to r16 global-load form (r17 LDS staging regressed: L1
// already dedupes shared K/V reads; barriers killed overlap) + keep tree-max /
// permlane reduces. NEW: 128^2-tile gemm128 for Q-proj (split) and out-proj
// (single) — the biggest non-attn cost (ladder: 64^2->128^2 ~ 1.5-1.7x).

#define B_   2
#define S_   2048
#define D_   1024
#define H_   16
#define DH_  64
#define MTOT (B_ * S_)  // 4096
#define NSPL 4

typedef short bf16x8 __attribute__((ext_vector_type(8)));
typedef float f32x4 __attribute__((ext_vector_type(4)));
typedef float f32x16 __attribute__((ext_vector_type(16)));
typedef short short4v __attribute__((ext_vector_type(4)));
typedef unsigned uint4v __attribute__((ext_vector_type(4)));

__device__ __forceinline__ short f2bf(float f) {  // RNE f32->bf16
  unsigned u = __float_as_uint(f);
  u += 0x7FFF + ((u >> 16) & 1);
  return (short)(u >> 16);
}
__device__ __forceinline__ float bf2f(short h) {
  return __uint_as_float(((unsigned)(unsigned short)h) << 16);
}
struct bfpair { short hi, lo; };
__device__ __forceinline__ bfpair split2(float x) {
  bfpair p;
  p.hi = f2bf(x);
  p.lo = f2bf(x - bf2f(p.hi));
  return p;
}
__device__ __forceinline__ unsigned cvtpk(float lo, float hi) {
  unsigned r;
  asm("v_cvt_pk_bf16_f32 %0, %1, %2" : "=v"(r) : "v"(lo), "v"(hi));
  return r;
}
// cross-half (lane ^ 32) pair via permlane32_swap: per lane returns {x[l], x[l^32]}
__device__ __forceinline__ float2 xhalf(float x) {
  unsigned u = __float_as_uint(x);
  auto sw = __builtin_amdgcn_permlane32_swap(u, u, false, false);
  return make_float2(__uint_as_float(sw[0]), __uint_as_float(sw[1]));
}

__device__ __forceinline__ void glds16(const void* g, void* l) {
  __builtin_amdgcn_global_load_lds((const __attribute__((address_space(1))) void*)g,
                                   (__attribute__((address_space(3))) void*)l, 16, 0, 0);
}

// ---------------- f32 -> bf16 convert; hi/lo split for q,k,wq,wk only ----------------
__global__ __launch_bounds__(256) void cvt_split(
    const float* __restrict__ q, const float* __restrict__ k, const float* __restrict__ v,
    const float* __restrict__ wq, const float* __restrict__ wk, const float* __restrict__ wv,
    const float* __restrict__ wo,
    short* qhi, short* qlo, short* khi, short* klo, short* vb,
    short* wqh, short* wql, short* wkh, short* wkl, short* wvb, short* wob) {
  const int U0 = 1048576, U1 = 2097152, U2 = 3145728, U3 = 3407872,
            U4 = 3424256, U5 = 3440640, U6 = 3702784;
  for (int u = blockIdx.x * blockDim.x + threadIdx.x; u < U6; u += gridDim.x * blockDim.x) {
    const float* s; short* dh; short* dl; int r;
    if (u < U0)      { s = q;  dh = qhi; dl = qlo; r = u; }
    else if (u < U1) { s = k;  dh = khi; dl = klo; r = u - U0; }
    else if (u < U2) { s = v;  dh = vb;  dl = nullptr; r = u - U1; }
    else if (u < U3) { s = wq; dh = wqh; dl = wql; r = u - U2; }
    else if (u < U4) { s = wk; dh = wkh; dl = wkl; r = u - U3; }
    else if (u < U5) { s = wv; dh = wvb; dl = nullptr; r = u - U4; }
    else             { s = wo; dh = wob; dl = nullptr; r = u - U5; }
    float4 x = *(const float4*)(s + (size_t)r * 4);
    bfpair p0 = split2(x.x), p1 = split2(x.y), p2 = split2(x.z), p3 = split2(x.w);
    short4v yh, yl;
    yh.x = p0.hi; yh.y = p1.hi; yh.z = p2.hi; yh.w = p3.hi;
    yl.x = p0.lo; yl.y = p1.lo; yl.z = p2.lo; yl.w = p3.lo;
    *(short4v*)(dh + (size_t)r * 4) = yh;
    if (dl) *(short4v*)(dl + (size_t)r * 4) = yl;
  }
}

// ---------------- 64^2-tile GEMM (kept for K/V projections, N=64) ----------------
// MODE 4: K-fragment-packed split pair  PK[tok>>5][dh>>4][(tok&31)+32*((dh>>3)&1)][dh&7]
// MODE 5: V-fragment-packed single bf16 PV[tok>>5][dh>>5][(tok>>4)&1][(dh&31)+32*((tok>>3)&1)][tok&7]
template <int NPROD, int MODE>
__global__ __launch_bounds__(256) void gemm3(
    const short* __restrict__ Ah, const short* __restrict__ Al,
    const short* __restrict__ Bh, const short* __restrict__ Bl,
    short* __restrict__ Ch, short* __restrict__ Cl, float* __restrict__ Cf,
    int K, int lda, int ldb, int ldc, float alpha) {
  __shared__ alignas(16) short Ash[4096], Asl[4096], Bsh[4096], Bsl[4096];
  const int tid = threadIdx.x;
  const int lane = tid & 63, w = tid >> 6;
  const int c = lane & 15, g = lane >> 4;
  const int wm = w >> 1, wn = w & 1;
  const int bm = blockIdx.x * 64, bn = blockIdx.y * 64;
  const int sr = lane >> 3;
  const int scs = ((lane & 7) ^ sr) * 8;

  f32x4 acc[2][2] = {};
  for (int k0 = 0; k0 < K; k0 += 64) {
    glds16(Ah + (size_t)(bm + w * 8 + sr) * lda + k0 + scs,      Ash + w * 512);
    glds16(Ah + (size_t)(bm + 32 + w * 8 + sr) * lda + k0 + scs, Ash + 2048 + w * 512);
    glds16(Bh + (size_t)(bn + w * 8 + sr) * ldb + k0 + scs,      Bsh + w * 512);
    glds16(Bh + (size_t)(bn + 32 + w * 8 + sr) * ldb + k0 + scs, Bsh + 2048 + w * 512);
    if constexpr (NPROD == 3) {
      glds16(Al + (size_t)(bm + w * 8 + sr) * lda + k0 + scs,      Asl + w * 512);
      glds16(Al + (size_t)(bm + 32 + w * 8 + sr) * lda + k0 + scs, Asl + 2048 + w * 512);
      glds16(Bl + (size_t)(bn + w * 8 + sr) * ldb + k0 + scs,      Bsl + w * 512);
      glds16(Bl + (size_t)(bn + 32 + w * 8 + sr) * ldb + k0 + scs, Bsl + 2048 + w * 512);
    }
    __syncthreads();
#pragma unroll
    for (int kk = 0; kk < 2; ++kk) {
      bf16x8 ah[2], bh[2], al[2], bl[2];
#pragma unroll
      for (int mt = 0; mt < 2; ++mt) {
        int row = wm * 32 + mt * 16 + c;
        int so = row * 64 + (((kk * 4 + g) ^ (row & 7)) * 8);
        ah[mt] = *(const bf16x8*)(Ash + so);
        if constexpr (NPROD == 3) al[mt] = *(const bf16x8*)(Asl + so);
      }
#pragma unroll
      for (int nt = 0; nt < 2; ++nt) {
        int row = wn * 32 + nt * 16 + c;
        int so = row * 64 + (((kk * 4 + g) ^ (row & 7)) * 8);
        bh[nt] = *(const bf16x8*)(Bsh + so);
        if constexpr (NPROD == 3) bl[nt] = *(const bf16x8*)(Bsl + so);
      }
#pragma unroll
      for (int mt = 0; mt < 2; ++mt)
#pragma unroll
        for (int nt = 0; nt < 2; ++nt) {
          acc[mt][nt] = __builtin_amdgcn_mfma_f32_16x16x32_bf16(ah[mt], bh[nt], acc[mt][nt], 0, 0, 0);
          if constexpr (NPROD == 3) {
            acc[mt][nt] = __builtin_amdgcn_mfma_f32_16x16x32_bf16(ah[mt], bl[nt], acc[mt][nt], 0, 0, 0);
            acc[mt][nt] = __builtin_amdgcn_mfma_f32_16x16x32_bf16(al[mt], bh[nt], acc[mt][nt], 0, 0, 0);
          }
        }
    }
    __syncthreads();
  }
#pragma unroll
  for (int mt = 0; mt < 2; ++mt) {
#pragma unroll
    for (int nt = 0; nt < 2; ++nt) {
#pragma unroll
      for (int r = 0; r < 4; ++r) {
        int m = bm + wm * 32 + mt * 16 + g * 4 + r;   // row (token)
        int n = bn + wn * 32 + nt * 16 + c;           // col (dh)
        float val = acc[mt][nt][r] * alpha;
        if constexpr (MODE == 4) {
          size_t off = (((size_t)(m >> 5) * 4 + (n >> 4)) * 64 +
                        ((m & 31) + 32 * ((n >> 3) & 1))) * 8 + (n & 7);
          bfpair pr = split2(val);
          Ch[off] = pr.hi;
          Cl[off] = pr.lo;
        } else {  // MODE 5
          size_t off = ((((size_t)(m >> 5) * 2 + (n >> 5)) * 2 + ((m >> 4) & 1)) * 64 +
                        ((n & 31) + 32 * ((m >> 3) & 1))) * 8 + (m & 7);
          Ch[off] = f2bf(val);
        }
      }
    }
  }
}

// ---------------- 128^2-tile GEMM (Q-proj split, out-proj single) ----------------
// BK=64, 4 waves (2x2), each wave 64x64 out = 4x4 16^2 frags. Same staging/swizzle
// formulas as gemm3. MODE 0: split pair row-major. MODE 3: f32 row-major.
template <int NPROD, int MODE>
__global__ __launch_bounds__(256) void gemm128(
    const short* __restrict__ Ah, const short* __restrict__ Al,
    const short* __restrict__ Bh, const short* __restrict__ Bl,
    short* __restrict__ Ch, short* __restrict__ Cl, float* __restrict__ Cf,
    int K, int lda, int ldb, int ldc, float alpha) {
  constexpr bool SPLIT = (NPROD == 3);
  __shared__ alignas(16) short Ash[8192];
  __shared__ alignas(16) short Bsh[8192];
  __shared__ alignas(16) short Asl[SPLIT ? 8192 : 16];
  __shared__ alignas(16) short Bsl[SPLIT ? 8192 : 16];
  const int tid = threadIdx.x;
  const int lane = tid & 63, w = tid >> 6;
  const int c = lane & 15, g = lane >> 4;
  const int wm = w >> 1, wn = w & 1;
  const int bm = blockIdx.x * 128, bn = blockIdx.y * 128;
  const int sr = lane >> 3;
  const int scs = ((lane & 7) ^ sr) * 8;

  f32x4 acc[4][4] = {};
  for (int k0 = 0; k0 < K; k0 += 64) {
#pragma unroll
    for (int i = 0; i < 4; ++i) {
      int rowb = i * 32 + w * 8;  // this wave stages rows rowb..rowb+7
      glds16(Ah + (size_t)(bm + rowb + sr) * lda + k0 + scs, Ash + rowb * 64);
      glds16(Bh + (size_t)(bn + rowb + sr) * ldb + k0 + scs, Bsh + rowb * 64);
      if constexpr (SPLIT) {
        glds16(Al + (size_t)(bm + rowb + sr) * lda + k0 + scs, Asl + rowb * 64);
        glds16(Bl + (size_t)(bn + rowb + sr) * ldb + k0 + scs, Bsl + rowb * 64);
      }
    }
    __syncthreads();
#pragma unroll
    for (int kk = 0; kk < 2; ++kk) {
      bf16x8 ah[4], bh[4], al[4], bl[4];
#pragma unroll
      for (int mt = 0; mt < 4; ++mt) {
        int row = wm * 64 + mt * 16 + c;
        int so = row * 64 + (((kk * 4 + g) ^ (row & 7)) * 8);
        ah[mt] = *(const bf16x8*)(Ash + so);
        if constexpr (SPLIT) al[mt] = *(const bf16x8*)(Asl + so);
      }
#pragma unroll
      for (int nt = 0; nt < 4; ++nt) {
        int row = wn * 64 + nt * 16 + c;
        int so = row * 64 + (((kk * 4 + g) ^ (row & 7)) * 8);
        bh[nt] = *(const bf16x8*)(Bsh + so);
        if constexpr (SPLIT) bl[nt] = *(const bf16x8*)(Bsl + so);
      }
#pragma unroll
      for (int mt = 0; mt < 4; ++mt)
#pragma unroll
        for (int nt = 0; nt < 4; ++nt) {
          acc[mt][nt] = __builtin_amdgcn_mfma_f32_16x16x32_bf16(ah[mt], bh[nt], acc[mt][nt], 0, 0, 0);
          if constexpr (SPLIT) {
            acc[mt][nt] = __builtin_amdgcn_mfma_f32_16x16x32_bf16(ah[mt], bl[nt], acc[mt][nt], 0, 0, 0);
            acc[mt][nt] = __builtin_amdgcn_mfma_f32_16x16x32_bf16(al[mt], bh[nt], acc[mt][nt], 0, 0, 0);
          }
        }
    }
    __syncthreads();
  }
#pragma unroll
  for (int mt = 0; mt < 4; ++mt) {
#pragma unroll
    for (int nt = 0; nt < 4; ++nt) {
#pragma unroll
      for (int r = 0; r < 4; ++r) {
        int m = bm + wm * 64 + mt * 16 + g * 4 + r;
        int n = bn + wn * 64 + nt * 16 + c;
        float val = acc[mt][nt][r] * alpha;
        if constexpr (MODE == 0) {
          bfpair pr = split2(val);
          Ch[(size_t)m * ldc + n] = pr.hi;
          Cl[(size_t)m * ldc + n] = pr.lo;
        } else {  // MODE 3
          Cf[(size_t)m * ldc + n] = val;
        }
      }
    }
  }
}

// ---------------- flash MQA attention (r16 form + fast reduces) ----------------
// grid (S/128, H, B*NSPL), 256 thr = 4 waves; wave w owns 32 q-rows; kv range = S/4.
__global__ __launch_bounds__(256) void mqa_attn(
    const short* __restrict__ qph, const short* __restrict__ qpl,
    const short* __restrict__ pkh, const short* __restrict__ pkl,
    const short* __restrict__ pv, short* __restrict__ pO, float* __restrict__ pML) {
  const int tid = threadIdx.x;
  const int lane = tid & 63, w = tid >> 6;
  const int j = lane & 31, b5 = lane >> 5;
  const int qt = blockIdx.x, h = blockIdx.y;
  const int b = blockIdx.z >> 2, sp = blockIdx.z & 3;
  const int q0 = qt * 128 + w * 32;
  const int kvbeg = sp * (S_ / NSPL), kvend = kvbeg + S_ / NSPL;

  const size_t qbase = (size_t)(b * S_ + q0 + j) * D_ + h * DH_ + b5 * 8;
  bf16x8 qh[4], ql[4];
#pragma unroll
  for (int m = 0; m < 4; ++m) {
    qh[m] = *(const bf16x8*)(qph + qbase + m * 16);
    ql[m] = *(const bf16x8*)(qpl + qbase + m * 16);
  }

  float mrow = -1.0e30f, lrow = 0.f;
  f32x16 o0 = {}, o1 = {};

  for (int kv0 = kvbeg; kv0 < kvend; kv0 += 32) {
    const size_t tg = (size_t)((b * S_ + kv0) >> 5);
    const short* kb = pkh + tg * 2048 + lane * 8;
    const short* kb2 = pkl + tg * 2048 + lane * 8;
    bf16x8 kh[4], kl[4];
#pragma unroll
    for (int m = 0; m < 4; ++m) {
      kh[m] = *(const bf16x8*)(kb + m * 512);
      kl[m] = *(const bf16x8*)(kb2 + m * 512);
    }
    f32x16 s = {};
#pragma unroll
    for (int m = 0; m < 4; ++m)
      s = __builtin_amdgcn_mfma_f32_32x32x16_bf16(kh[m], qh[m], s, 0, 0, 0);
#pragma unroll
    for (int m = 0; m < 4; ++m)
      s = __builtin_amdgcn_mfma_f32_32x32x16_bf16(kl[m], qh[m], s, 0, 0, 0);
#pragma unroll
    for (int m = 0; m < 4; ++m)
      s = __builtin_amdgcn_mfma_f32_32x32x16_bf16(kh[m], ql[m], s, 0, 0, 0);
    // ---- softmax: balanced max tree + permlane cross-half ----
    float a0 = fmaxf(s[0], s[1]), a1 = fmaxf(s[2], s[3]),
          a2 = fmaxf(s[4], s[5]), a3 = fmaxf(s[6], s[7]),
          a4 = fmaxf(s[8], s[9]), a5 = fmaxf(s[10], s[11]),
          a6 = fmaxf(s[12], s[13]), a7 = fmaxf(s[14], s[15]);
    float b0 = fmaxf(a0, a1), b1 = fmaxf(a2, a3), b2 = fmaxf(a4, a5), b3 = fmaxf(a6, a7);
    float mx = fmaxf(fmaxf(b0, b1), fmaxf(b2, b3));
    float2 xh = xhalf(mx);
    mx = fmaxf(xh.x, xh.y);
    if (!__all(mx - mrow <= 8.0f)) {
      float mn = fmaxf(mrow, mx);
      float scale = exp2f(mrow - mn);
      mrow = mn;
      lrow *= scale;
      o0 *= scale;
      o1 *= scale;
    }
    float p[16];
#pragma unroll
    for (int r = 0; r < 16; ++r) p[r] = exp2f(s[r] - mrow);
    float rs = (((p[0] + p[1]) + (p[2] + p[3])) + ((p[4] + p[5]) + (p[6] + p[7]))) +
               (((p[8] + p[9]) + (p[10] + p[11])) + ((p[12] + p[13]) + (p[14] + p[15])));
    float2 rh = xhalf(rs);
    rs = rh.x + rh.y;
    lrow += rs;
    // ---- P^T fragments via cvt_pk + permlane32_swap ----
    auto r0 = __builtin_amdgcn_permlane32_swap(cvtpk(p[0], p[1]),   cvtpk(p[4], p[5]),   false, false);
    auto r1 = __builtin_amdgcn_permlane32_swap(cvtpk(p[2], p[3]),   cvtpk(p[6], p[7]),   false, false);
    auto r2 = __builtin_amdgcn_permlane32_swap(cvtpk(p[8], p[9]),   cvtpk(p[12], p[13]), false, false);
    auto r3 = __builtin_amdgcn_permlane32_swap(cvtpk(p[10], p[11]), cvtpk(p[14], p[15]), false, false);
    union { uint4v u; bf16x8 v; } pa0, pa1;
    pa0.u = (uint4v){r0[0], r1[0], r0[1], r1[1]};  // kv 0..15 (per b5 half)
    pa1.u = (uint4v){r2[0], r3[0], r2[1], r3[1]};  // kv 16..31
    const short* vbp = pv + tg * 2048 + lane * 8;
    bf16x8 va00 = *(const bf16x8*)(vbp);
    bf16x8 va01 = *(const bf16x8*)(vbp + 512);
    bf16x8 va10 = *(const bf16x8*)(vbp + 1024);
    bf16x8 va11 = *(const bf16x8*)(vbp + 1536);
    o0 = __builtin_amdgcn_mfma_f32_32x32x16_bf16(va00, pa0.v, o0, 0, 0, 0);
    o0 = __builtin_amdgcn_mfma_f32_32x32x16_bf16(va01, pa1.v, o0, 0, 0, 0);
    o1 = __builtin_amdgcn_mfma_f32_32x32x16_bf16(va10, pa0.v, o1, 0, 0, 0);
    o1 = __builtin_amdgcn_mfma_f32_32x32x16_bf16(va11, pa1.v, o1, 0, 0, 0);
  }
  const size_t tok = (size_t)(b * S_ + q0 + j);
  const size_t obase = ((size_t)sp * MTOT + tok) * D_ + h * DH_;
#pragma unroll
  for (int r = 0; r < 16; ++r) {
    int dh0 = (r & 3) + 8 * (r >> 2) + 4 * b5;
    pO[obase + dh0] = f2bf(o0[r]);
    pO[obase + 32 + dh0] = f2bf(o1[r]);
  }
  if (b5 == 0) {
    size_t mb = (((size_t)sp * MTOT + tok) * H_ + h) * 2;
    pML[mb] = mrow;
    pML[mb + 1] = lrow;
  }
}

// ---------------- merge NSPL KV-split partials -> single bf16 ao ----------------
__global__ __launch_bounds__(256) void attn_merge(
    const short* __restrict__ pO, const float* __restrict__ pML,
    short* __restrict__ ao) {
  int qd = blockIdx.x * 256 + threadIdx.x;
  size_t idx = (size_t)qd * 4;
  int tok = (int)(idx >> 10);
  int h = (int)((idx >> 6) & 15);
  float ms[NSPL], ls[NSPL], mm = -1.0e30f;
#pragma unroll
  for (int s = 0; s < NSPL; ++s) {
    size_t mb = (((size_t)s * MTOT + tok) * H_ + h) * 2;
    ms[s] = pML[mb];
    ls[s] = pML[mb + 1];
    mm = fmaxf(mm, ms[s]);
  }
  float num[4] = {}, den = 0.f;
#pragma unroll
  for (int s = 0; s < NSPL; ++s) {
    float e = exp2f(ms[s] - mm);
    den += ls[s] * e;
    short4v o4 = *(const short4v*)(pO + (size_t)s * MTOT * D_ + idx);
    num[0] += bf2f(o4.x) * e;
    num[1] += bf2f(o4.y) * e;
    num[2] += bf2f(o4.z) * e;
    num[3] += bf2f(o4.w) * e;
  }
  float inv = 1.0f / den;
  short4v y;
  y.x = f2bf(num[0] * inv);
  y.y = f2bf(num[1] * inv);
  y.z = f2bf(num[2] * inv);
  y.w = f2bf(num[3] * inv);
  *(short4v*)(ao + idx) = y;
}

// ---------------- launch ----------------
extern "C" void kernel_launch(void* const* d_in, const int* in_sizes, int n_in,
                              void* d_out, int out_size, void* d_ws, size_t ws_size,
                              hipStream_t stream) {
  const float* q  = (const float*)d_in[0];
  const float* k  = (const float*)d_in[1];
  const float* v  = (const float*)d_in[2];
  const float* wq = (const float*)d_in[3];
  const float* wk = (const float*)d_in[4];
  const float* wv = (const float*)d_in[5];
  const float* wo = (const float*)d_in[6];

  short* p = (short*)d_ws;
  short* qhi = p; p += 4194304;   // dead after Q-proj -> pO splits 0,1
  short* qlo = p; p += 4194304;
  short* khi = p; p += 4194304;   // dead after K-proj -> pO splits 2,3
  short* klo = p; p += 4194304;
  short* vb  = p; p += 4194304;   // dead after V-proj -> pML
  short* wqh = p; p += 1048576;
  short* wql = p; p += 1048576;
  short* wkh = p; p += 65536;
  short* wkl = p; p += 65536;
  short* wvb = p; p += 65536;
  short* wob = p; p += 1048576;
  short* qph = p; p += 4194304;   // dead after attn -> ao
  short* qpl = p; p += 4194304;
  short* pkh = p; p += 524288;    // packed K hi [128 tiles][4][64][8]
  short* pkl = p; p += 524288;    // packed K lo
  short* pv  = p; p += 524288;    // packed V^T [128 tiles][2][2][64][8]
  short* pO  = qhi;               // [NSPL][4096][1024] bf16 = 33.6 MB
  float* pML = (float*)vb;        // [NSPL][4096][16][2] f32 = 2 MB
  short* ao  = qph;               // merge runs after attn reads qph/qpl

  cvt_split<<<dim3(2048), dim3(256), 0, stream>>>(q, k, v, wq, wk, wv, wo,
      qhi, qlo, khi, klo, vb, wqh, wql, wkh, wkl, wvb, wob);
  // qp = q @ wq^T * (0.125 * log2e)  -> exp2-domain scores  (128^2 tile, split)
  gemm128<3, 0><<<dim3(32, 8), dim3(256), 0, stream>>>(qhi, qlo, wqh, wql, qph, qpl,
      nullptr, 1024, 1024, 1024, 1024, 0.125f * 1.44269504f);
  // kp -> packed fragment layout (split)
  gemm3<3, 4><<<dim3(64, 1), dim3(256), 0, stream>>>(khi, klo, wkh, wkl, pkh, pkl,
      nullptr, 1024, 1024, 1024, 64, 1.0f);
  // vp -> packed V^T fragment layout
  gemm3<1, 5><<<dim3(64, 1), dim3(256), 0, stream>>>(vb, nullptr, wvb, nullptr, pv,
      nullptr, nullptr, 1024, 1024, 1024, 64, 1.0f);
  mqa_attn<<<dim3(S_ / 128, 16, B_ * NSPL), dim3(256), 0, stream>>>(
      qph, qpl, pkh, pkl, pv, pO, pML);
  attn_merge<<<dim3(MTOT * D_ / 4 / 256), dim3(256), 0, stream>>>(pO, pML, ao);
  // d_out(f32) = ao @ wo^T  (128^2 tile, single bf16)
  gemm128<1, 3><<<dim3(32, 8), dim3(256), 0, stream>>>(ao, nullptr, wob, nullptr,
      nullptr, nullptr, (float*)d_out, 1024, 1024, 1024, 1024, 1.0f);
}

// Round 19
// 203.070 us; speedup vs baseline: 1.1966x; 1.0696x over previous
//
#include <hip/hip_runtime.h>
#include <hip/hip_bf16.h>
#include <stdint.h>

// MQA: B=2, S=2048, D=1024, H=16, DH=64. Inputs f32, OUTPUT f32.
// r19: exact r16 config (best: 203.1us) + T5 s_setprio(1) around attn MFMA
// clusters (m191: +4-7% attn in barrier-free multi-phase regime).
// r18 post-mortem: tree-max/xhalf (-5us) and gemm128@1-block/CU (-9us) both
// reverted.

#define B_   2
#define S_   2048
#define D_   1024
#define H_   16
#define DH_  64
#define MTOT (B_ * S_)  // 4096
#define NSPL 4

typedef short bf16x8 __attribute__((ext_vector_type(8)));
typedef float f32x4 __attribute__((ext_vector_type(4)));
typedef float f32x16 __attribute__((ext_vector_type(16)));
typedef short short4v __attribute__((ext_vector_type(4)));
typedef unsigned uint4v __attribute__((ext_vector_type(4)));

__device__ __forceinline__ short f2bf(float f) {  // RNE f32->bf16
  unsigned u = __float_as_uint(f);
  u += 0x7FFF + ((u >> 16) & 1);
  return (short)(u >> 16);
}
__device__ __forceinline__ float bf2f(short h) {
  return __uint_as_float(((unsigned)(unsigned short)h) << 16);
}
struct bfpair { short hi, lo; };
__device__ __forceinline__ bfpair split2(float x) {
  bfpair p;
  p.hi = f2bf(x);
  p.lo = f2bf(x - bf2f(p.hi));
  return p;
}
__device__ __forceinline__ unsigned cvtpk(float lo, float hi) {
  unsigned r;
  asm("v_cvt_pk_bf16_f32 %0, %1, %2" : "=v"(r) : "v"(lo), "v"(hi));
  return r;
}

__device__ __forceinline__ void glds16(const void* g, void* l) {
  __builtin_amdgcn_global_load_lds((const __attribute__((address_space(1))) void*)g,
                                   (__attribute__((address_space(3))) void*)l, 16, 0, 0);
}

// ---------------- f32 -> bf16 convert; hi/lo split for q,k,wq,wk only ----------------
__global__ __launch_bounds__(256) void cvt_split(
    const float* __restrict__ q, const float* __restrict__ k, const float* __restrict__ v,
    const float* __restrict__ wq, const float* __restrict__ wk, const float* __restrict__ wv,
    const float* __restrict__ wo,
    short* qhi, short* qlo, short* khi, short* klo, short* vb,
    short* wqh, short* wql, short* wkh, short* wkl, short* wvb, short* wob) {
  const int U0 = 1048576, U1 = 2097152, U2 = 3145728, U3 = 3407872,
            U4 = 3424256, U5 = 3440640, U6 = 3702784;
  for (int u = blockIdx.x * blockDim.x + threadIdx.x; u < U6; u += gridDim.x * blockDim.x) {
    const float* s; short* dh; short* dl; int r;
    if (u < U0)      { s = q;  dh = qhi; dl = qlo; r = u; }
    else if (u < U1) { s = k;  dh = khi; dl = klo; r = u - U0; }
    else if (u < U2) { s = v;  dh = vb;  dl = nullptr; r = u - U1; }
    else if (u < U3) { s = wq; dh = wqh; dl = wql; r = u - U2; }
    else if (u < U4) { s = wk; dh = wkh; dl = wkl; r = u - U3; }
    else if (u < U5) { s = wv; dh = wvb; dl = nullptr; r = u - U4; }
    else             { s = wo; dh = wob; dl = nullptr; r = u - U5; }
    float4 x = *(const float4*)(s + (size_t)r * 4);
    bfpair p0 = split2(x.x), p1 = split2(x.y), p2 = split2(x.z), p3 = split2(x.w);
    short4v yh, yl;
    yh.x = p0.hi; yh.y = p1.hi; yh.z = p2.hi; yh.w = p3.hi;
    yl.x = p0.lo; yl.y = p1.lo; yl.z = p2.lo; yl.w = p3.lo;
    *(short4v*)(dh + (size_t)r * 4) = yh;
    if (dl) *(short4v*)(dl + (size_t)r * 4) = yl;
  }
}

// ---------------- GEMM  C = (Ah+Al) * (Bh+Bl)^T, f32 acc ----------------
// MODE 0: split pair row-major. MODE 3: f32 row-major.
// MODE 4: K-fragment-packed split pair  PK[tok>>5][dh>>4][(tok&31)+32*((dh>>3)&1)][dh&7]
// MODE 5: V-fragment-packed single bf16 PV[tok>>5][dh>>5][(tok>>4)&1][(dh&31)+32*((tok>>3)&1)][tok&7]
template <int NPROD, int MODE>
__global__ __launch_bounds__(256) void gemm3(
    const short* __restrict__ Ah, const short* __restrict__ Al,
    const short* __restrict__ Bh, const short* __restrict__ Bl,
    short* __restrict__ Ch, short* __restrict__ Cl, float* __restrict__ Cf,
    int K, int lda, int ldb, int ldc, float alpha) {
  __shared__ alignas(16) short Ash[4096], Asl[4096], Bsh[4096], Bsl[4096];
  const int tid = threadIdx.x;
  const int lane = tid & 63, w = tid >> 6;
  const int c = lane & 15, g = lane >> 4;
  const int wm = w >> 1, wn = w & 1;
  const int bm = blockIdx.x * 64, bn = blockIdx.y * 64;
  const int sr = lane >> 3;
  const int scs = ((lane & 7) ^ sr) * 8;

  f32x4 acc[2][2] = {};
  for (int k0 = 0; k0 < K; k0 += 64) {
    glds16(Ah + (size_t)(bm + w * 8 + sr) * lda + k0 + scs,      Ash + w * 512);
    glds16(Ah + (size_t)(bm + 32 + w * 8 + sr) * lda + k0 + scs, Ash + 2048 + w * 512);
    glds16(Bh + (size_t)(bn + w * 8 + sr) * ldb + k0 + scs,      Bsh + w * 512);
    glds16(Bh + (size_t)(bn + 32 + w * 8 + sr) * ldb + k0 + scs, Bsh + 2048 + w * 512);
    if constexpr (NPROD == 3) {
      glds16(Al + (size_t)(bm + w * 8 + sr) * lda + k0 + scs,      Asl + w * 512);
      glds16(Al + (size_t)(bm + 32 + w * 8 + sr) * lda + k0 + scs, Asl + 2048 + w * 512);
      glds16(Bl + (size_t)(bn + w * 8 + sr) * ldb + k0 + scs,      Bsl + w * 512);
      glds16(Bl + (size_t)(bn + 32 + w * 8 + sr) * ldb + k0 + scs, Bsl + 2048 + w * 512);
    }
    __syncthreads();
#pragma unroll
    for (int kk = 0; kk < 2; ++kk) {
      bf16x8 ah[2], bh[2], al[2], bl[2];
#pragma unroll
      for (int mt = 0; mt < 2; ++mt) {
        int row = wm * 32 + mt * 16 + c;
        int so = row * 64 + (((kk * 4 + g) ^ (row & 7)) * 8);
        ah[mt] = *(const bf16x8*)(Ash + so);
        if constexpr (NPROD == 3) al[mt] = *(const bf16x8*)(Asl + so);
      }
#pragma unroll
      for (int nt = 0; nt < 2; ++nt) {
        int row = wn * 32 + nt * 16 + c;
        int so = row * 64 + (((kk * 4 + g) ^ (row & 7)) * 8);
        bh[nt] = *(const bf16x8*)(Bsh + so);
        if constexpr (NPROD == 3) bl[nt] = *(const bf16x8*)(Bsl + so);
      }
#pragma unroll
      for (int mt = 0; mt < 2; ++mt)
#pragma unroll
        for (int nt = 0; nt < 2; ++nt) {
          acc[mt][nt] = __builtin_amdgcn_mfma_f32_16x16x32_bf16(ah[mt], bh[nt], acc[mt][nt], 0, 0, 0);
          if constexpr (NPROD == 3) {
            acc[mt][nt] = __builtin_amdgcn_mfma_f32_16x16x32_bf16(ah[mt], bl[nt], acc[mt][nt], 0, 0, 0);
            acc[mt][nt] = __builtin_amdgcn_mfma_f32_16x16x32_bf16(al[mt], bh[nt], acc[mt][nt], 0, 0, 0);
          }
        }
    }
    __syncthreads();
  }
#pragma unroll
  for (int mt = 0; mt < 2; ++mt) {
#pragma unroll
    for (int nt = 0; nt < 2; ++nt) {
#pragma unroll
      for (int r = 0; r < 4; ++r) {
        int m = bm + wm * 32 + mt * 16 + g * 4 + r;   // row (token)
        int n = bn + wn * 32 + nt * 16 + c;           // col (dh / N)
        float val = acc[mt][nt][r] * alpha;
        if constexpr (MODE == 0) {
          bfpair pr = split2(val);
          Ch[(size_t)m * ldc + n] = pr.hi;
          Cl[(size_t)m * ldc + n] = pr.lo;
        } else if constexpr (MODE == 3) {
          Cf[(size_t)m * ldc + n] = val;
        } else if constexpr (MODE == 4) {
          size_t off = (((size_t)(m >> 5) * 4 + (n >> 4)) * 64 +
                        ((m & 31) + 32 * ((n >> 3) & 1))) * 8 + (n & 7);
          bfpair pr = split2(val);
          Ch[off] = pr.hi;
          Cl[off] = pr.lo;
        } else {  // MODE 5
          size_t off = ((((size_t)(m >> 5) * 2 + (n >> 5)) * 2 + ((m >> 4) & 1)) * 64 +
                        ((n & 31) + 32 * ((m >> 3) & 1))) * 8 + (m & 7);
          Ch[off] = f2bf(val);
        }
      }
    }
  }
}

// ---------------- flash MQA attention (r16 form + setprio around MFMA) ----------
// grid (S/128, H, B*NSPL), 256 thr = 4 waves; wave w owns 32 q-rows; kv range = S/4.
__global__ __launch_bounds__(256) void mqa_attn(
    const short* __restrict__ qph, const short* __restrict__ qpl,
    const short* __restrict__ pkh, const short* __restrict__ pkl,
    const short* __restrict__ pv, short* __restrict__ pO, float* __restrict__ pML) {
  const int tid = threadIdx.x;
  const int lane = tid & 63, w = tid >> 6;
  const int j = lane & 31, b5 = lane >> 5;
  const int qt = blockIdx.x, h = blockIdx.y;
  const int b = blockIdx.z >> 2, sp = blockIdx.z & 3;
  const int q0 = qt * 128 + w * 32;
  const int kvbeg = sp * (S_ / NSPL), kvend = kvbeg + S_ / NSPL;

  const size_t qbase = (size_t)(b * S_ + q0 + j) * D_ + h * DH_ + b5 * 8;
  bf16x8 qh[4], ql[4];
#pragma unroll
  for (int m = 0; m < 4; ++m) {
    qh[m] = *(const bf16x8*)(qph + qbase + m * 16);
    ql[m] = *(const bf16x8*)(qpl + qbase + m * 16);
  }

  float mrow = -1.0e30f, lrow = 0.f;
  f32x16 o0 = {}, o1 = {};

  for (int kv0 = kvbeg; kv0 < kvend; kv0 += 32) {
    const size_t tg = (size_t)((b * S_ + kv0) >> 5);
    const short* kb = pkh + tg * 2048 + lane * 8;
    const short* kb2 = pkl + tg * 2048 + lane * 8;
    bf16x8 kh[4], kl[4];
#pragma unroll
    for (int m = 0; m < 4; ++m) {
      kh[m] = *(const bf16x8*)(kb + m * 512);
      kl[m] = *(const bf16x8*)(kb2 + m * 512);
    }
    // ---- scores: 12 MFMAs chained into ONE accumulator (setprio cluster) ----
    f32x16 s = {};
    __builtin_amdgcn_s_setprio(1);
#pragma unroll
    for (int m = 0; m < 4; ++m)
      s = __builtin_amdgcn_mfma_f32_32x32x16_bf16(kh[m], qh[m], s, 0, 0, 0);
#pragma unroll
    for (int m = 0; m < 4; ++m)
      s = __builtin_amdgcn_mfma_f32_32x32x16_bf16(kl[m], qh[m], s, 0, 0, 0);
#pragma unroll
    for (int m = 0; m < 4; ++m)
      s = __builtin_amdgcn_mfma_f32_32x32x16_bf16(kh[m], ql[m], s, 0, 0, 0);
    __builtin_amdgcn_s_setprio(0);
    // ---- in-register online softmax with defer-max (THR = 8, log2 domain) ----
    float mx = s[0];
#pragma unroll
    for (int r = 1; r < 16; ++r) mx = fmaxf(mx, s[r]);
    mx = fmaxf(mx, __shfl_xor(mx, 32));
    if (!__all(mx - mrow <= 8.0f)) {
      float mn = fmaxf(mrow, mx);
      float scale = exp2f(mrow - mn);
      mrow = mn;
      lrow *= scale;
      o0 *= scale;
      o1 *= scale;
    }
    float p[16];
#pragma unroll
    for (int r = 0; r < 16; ++r) p[r] = exp2f(s[r] - mrow);
    float rs = (((p[0] + p[1]) + (p[2] + p[3])) + ((p[4] + p[5]) + (p[6] + p[7]))) +
               (((p[8] + p[9]) + (p[10] + p[11])) + ((p[12] + p[13]) + (p[14] + p[15])));
    rs += __shfl_xor(rs, 32);
    lrow += rs;
    // ---- P^T fragments via cvt_pk + permlane32_swap ----
    auto r0 = __builtin_amdgcn_permlane32_swap(cvtpk(p[0], p[1]),   cvtpk(p[4], p[5]),   false, false);
    auto r1 = __builtin_amdgcn_permlane32_swap(cvtpk(p[2], p[3]),   cvtpk(p[6], p[7]),   false, false);
    auto r2 = __builtin_amdgcn_permlane32_swap(cvtpk(p[8], p[9]),   cvtpk(p[12], p[13]), false, false);
    auto r3 = __builtin_amdgcn_permlane32_swap(cvtpk(p[10], p[11]), cvtpk(p[14], p[15]), false, false);
    union { uint4v u; bf16x8 v; } pa0, pa1;
    pa0.u = (uint4v){r0[0], r1[0], r0[1], r1[1]};  // kv 0..15 (per b5 half)
    pa1.u = (uint4v){r2[0], r3[0], r2[1], r3[1]};  // kv 16..31
    // ---- O^T += V^T x P^T (setprio cluster) ----
    const short* vbp = pv + tg * 2048 + lane * 8;
    bf16x8 va00 = *(const bf16x8*)(vbp);
    bf16x8 va01 = *(const bf16x8*)(vbp + 512);
    bf16x8 va10 = *(const bf16x8*)(vbp + 1024);
    bf16x8 va11 = *(const bf16x8*)(vbp + 1536);
    __builtin_amdgcn_s_setprio(1);
    o0 = __builtin_amdgcn_mfma_f32_32x32x16_bf16(va00, pa0.v, o0, 0, 0, 0);
    o0 = __builtin_amdgcn_mfma_f32_32x32x16_bf16(va01, pa1.v, o0, 0, 0, 0);
    o1 = __builtin_amdgcn_mfma_f32_32x32x16_bf16(va10, pa0.v, o1, 0, 0, 0);
    o1 = __builtin_amdgcn_mfma_f32_32x32x16_bf16(va11, pa1.v, o1, 0, 0, 0);
    __builtin_amdgcn_s_setprio(0);
  }
  const size_t tok = (size_t)(b * S_ + q0 + j);
  const size_t obase = ((size_t)sp * MTOT + tok) * D_ + h * DH_;
#pragma unroll
  for (int r = 0; r < 16; ++r) {
    int dh0 = (r & 3) + 8 * (r >> 2) + 4 * b5;
    pO[obase + dh0] = f2bf(o0[r]);
    pO[obase + 32 + dh0] = f2bf(o1[r]);
  }
  if (b5 == 0) {
    size_t mb = (((size_t)sp * MTOT + tok) * H_ + h) * 2;
    pML[mb] = mrow;
    pML[mb + 1] = lrow;
  }
}

// ---------------- merge NSPL KV-split partials -> single bf16 ao ----------------
__global__ __launch_bounds__(256) void attn_merge(
    const short* __restrict__ pO, const float* __restrict__ pML,
    short* __restrict__ ao) {
  int qd = blockIdx.x * 256 + threadIdx.x;
  size_t idx = (size_t)qd * 4;
  int tok = (int)(idx >> 10);
  int h = (int)((idx >> 6) & 15);
  float ms[NSPL], ls[NSPL], mm = -1.0e30f;
#pragma unroll
  for (int s = 0; s < NSPL; ++s) {
    size_t mb = (((size_t)s * MTOT + tok) * H_ + h) * 2;
    ms[s] = pML[mb];
    ls[s] = pML[mb + 1];
    mm = fmaxf(mm, ms[s]);
  }
  float num[4] = {}, den = 0.f;
#pragma unroll
  for (int s = 0; s < NSPL; ++s) {
    float e = exp2f(ms[s] - mm);
    den += ls[s] * e;
    short4v o4 = *(const short4v*)(pO + (size_t)s * MTOT * D_ + idx);
    num[0] += bf2f(o4.x) * e;
    num[1] += bf2f(o4.y) * e;
    num[2] += bf2f(o4.z) * e;
    num[3] += bf2f(o4.w) * e;
  }
  float inv = 1.0f / den;
  short4v y;
  y.x = f2bf(num[0] * inv);
  y.y = f2bf(num[1] * inv);
  y.z = f2bf(num[2] * inv);
  y.w = f2bf(num[3] * inv);
  *(short4v*)(ao + idx) = y;
}

// ---------------- launch ----------------
extern "C" void kernel_launch(void* const* d_in, const int* in_sizes, int n_in,
                              void* d_out, int out_size, void* d_ws, size_t ws_size,
                              hipStream_t stream) {
  const float* q  = (const float*)d_in[0];
  const float* k  = (const float*)d_in[1];
  const float* v  = (const float*)d_in[2];
  const float* wq = (const float*)d_in[3];
  const float* wk = (const float*)d_in[4];
  const float* wv = (const float*)d_in[5];
  const float* wo = (const float*)d_in[6];

  short* p = (short*)d_ws;
  short* qhi = p; p += 4194304;   // dead after Q-proj -> pO splits 0,1
  short* qlo = p; p += 4194304;
  short* khi = p; p += 4194304;   // dead after K-proj -> pO splits 2,3
  short* klo = p; p += 4194304;
  short* vb  = p; p += 4194304;   // dead after V-proj -> pML
  short* wqh = p; p += 1048576;
  short* wql = p; p += 1048576;
  short* wkh = p; p += 65536;
  short* wkl = p; p += 65536;
  short* wvb = p; p += 65536;
  short* wob = p; p += 1048576;
  short* qph = p; p += 4194304;   // dead after attn -> ao
  short* qpl = p; p += 4194304;
  short* pkh = p; p += 524288;    // packed K hi [128 tiles][4][64][8]
  short* pkl = p; p += 524288;    // packed K lo
  short* pv  = p; p += 524288;    // packed V^T [128 tiles][2][2][64][8]
  short* pO  = qhi;               // [NSPL][4096][1024] bf16 = 33.6 MB
  float* pML = (float*)vb;        // [NSPL][4096][16][2] f32 = 2 MB
  short* ao  = qph;               // merge runs after attn reads qph/qpl

  cvt_split<<<dim3(2048), dim3(256), 0, stream>>>(q, k, v, wq, wk, wv, wo,
      qhi, qlo, khi, klo, vb, wqh, wql, wkh, wkl, wvb, wob);
  // qp = q @ wq^T * (0.125 * log2e)  -> exp2-domain scores
  gemm3<3, 0><<<dim3(64, 16), dim3(256), 0, stream>>>(qhi, qlo, wqh, wql, qph, qpl,
      nullptr, 1024, 1024, 1024, 1024, 0.125f * 1.44269504f);
  // kp -> packed fragment layout (split)
  gemm3<3, 4><<<dim3(64, 1), dim3(256), 0, stream>>>(khi, klo, wkh, wkl, pkh, pkl,
      nullptr, 1024, 1024, 1024, 64, 1.0f);
  // vp -> packed V^T fragment layout
  gemm3<1, 5><<<dim3(64, 1), dim3(256), 0, stream>>>(vb, nullptr, wvb, nullptr, pv,
      nullptr, nullptr, 1024, 1024, 1024, 64, 1.0f);
  mqa_attn<<<dim3(S_ / 128, 16, B_ * NSPL), dim3(256), 0, stream>>>(
      qph, qpl, pkh, pkl, pv, pO, pML);
  attn_merge<<<dim3(MTOT * D_ / 4 / 256), dim3(256), 0, stream>>>(pO, pML, ao);
  // d_out(f32) = ao @ wo^T  (single bf16 — post-softmax path tolerates it)
  gemm3<1, 3><<<dim3(64, 16), dim3(256), 0, stream>>>(ao, nullptr, wob, nullptr,
      nullptr, nullptr, (float*)d_out, 1024, 1024, 1024, 1024, 1.0f);
}

// Round 20
// 192.388 us; speedup vs baseline: 1.2630x; 1.0555x over previous
//
#include <hip/hip_runtime.h>
#include <hip/hip_bf16.h>
#include <stdint.h>

// MQA: B=2, S=2048, D=1024, H=16, DH=64. Inputs f32, OUTPUT f32.
// r20: r19 config (best: 203.07us) + K-proj/V-proj fused into ONE launch
// (both were 64-block starved dispatches serialized back-to-back; fusing
// overlaps their tails). Everything else unchanged.

#define B_   2
#define S_   2048
#define D_   1024
#define H_   16
#define DH_  64
#define MTOT (B_ * S_)  // 4096
#define NSPL 4

typedef short bf16x8 __attribute__((ext_vector_type(8)));
typedef float f32x4 __attribute__((ext_vector_type(4)));
typedef float f32x16 __attribute__((ext_vector_type(16)));
typedef short short4v __attribute__((ext_vector_type(4)));
typedef unsigned uint4v __attribute__((ext_vector_type(4)));

__device__ __forceinline__ short f2bf(float f) {  // RNE f32->bf16
  unsigned u = __float_as_uint(f);
  u += 0x7FFF + ((u >> 16) & 1);
  return (short)(u >> 16);
}
__device__ __forceinline__ float bf2f(short h) {
  return __uint_as_float(((unsigned)(unsigned short)h) << 16);
}
struct bfpair { short hi, lo; };
__device__ __forceinline__ bfpair split2(float x) {
  bfpair p;
  p.hi = f2bf(x);
  p.lo = f2bf(x - bf2f(p.hi));
  return p;
}
__device__ __forceinline__ unsigned cvtpk(float lo, float hi) {
  unsigned r;
  asm("v_cvt_pk_bf16_f32 %0, %1, %2" : "=v"(r) : "v"(lo), "v"(hi));
  return r;
}

__device__ __forceinline__ void glds16(const void* g, void* l) {
  __builtin_amdgcn_global_load_lds((const __attribute__((address_space(1))) void*)g,
                                   (__attribute__((address_space(3))) void*)l, 16, 0, 0);
}

// ---------------- f32 -> bf16 convert; hi/lo split for q,k,wq,wk only ----------------
__global__ __launch_bounds__(256) void cvt_split(
    const float* __restrict__ q, const float* __restrict__ k, const float* __restrict__ v,
    const float* __restrict__ wq, const float* __restrict__ wk, const float* __restrict__ wv,
    const float* __restrict__ wo,
    short* qhi, short* qlo, short* khi, short* klo, short* vb,
    short* wqh, short* wql, short* wkh, short* wkl, short* wvb, short* wob) {
  const int U0 = 1048576, U1 = 2097152, U2 = 3145728, U3 = 3407872,
            U4 = 3424256, U5 = 3440640, U6 = 3702784;
  for (int u = blockIdx.x * blockDim.x + threadIdx.x; u < U6; u += gridDim.x * blockDim.x) {
    const float* s; short* dh; short* dl; int r;
    if (u < U0)      { s = q;  dh = qhi; dl = qlo; r = u; }
    else if (u < U1) { s = k;  dh = khi; dl = klo; r = u - U0; }
    else if (u < U2) { s = v;  dh = vb;  dl = nullptr; r = u - U1; }
    else if (u < U3) { s = wq; dh = wqh; dl = wql; r = u - U2; }
    else if (u < U4) { s = wk; dh = wkh; dl = wkl; r = u - U3; }
    else if (u < U5) { s = wv; dh = wvb; dl = nullptr; r = u - U4; }
    else             { s = wo; dh = wob; dl = nullptr; r = u - U5; }
    float4 x = *(const float4*)(s + (size_t)r * 4);
    bfpair p0 = split2(x.x), p1 = split2(x.y), p2 = split2(x.z), p3 = split2(x.w);
    short4v yh, yl;
    yh.x = p0.hi; yh.y = p1.hi; yh.z = p2.hi; yh.w = p3.hi;
    yl.x = p0.lo; yl.y = p1.lo; yl.z = p2.lo; yl.w = p3.lo;
    *(short4v*)(dh + (size_t)r * 4) = yh;
    if (dl) *(short4v*)(dl + (size_t)r * 4) = yl;
  }
}

// ---------------- GEMM body (device fn)  C = (Ah+Al) * (Bh+Bl)^T, f32 acc ----------
// MODE 0: split pair row-major. MODE 3: f32 row-major.
// MODE 4: K-fragment-packed split pair  PK[tok>>5][dh>>4][(tok&31)+32*((dh>>3)&1)][dh&7]
// MODE 5: V-fragment-packed single bf16 PV[tok>>5][dh>>5][(tok>>4)&1][(dh&31)+32*((tok>>3)&1)][tok&7]
template <int NPROD, int MODE>
__device__ __forceinline__ void gemm_body(
    const short* __restrict__ Ah, const short* __restrict__ Al,
    const short* __restrict__ Bh, const short* __restrict__ Bl,
    short* __restrict__ Ch, short* __restrict__ Cl, float* __restrict__ Cf,
    int K, int lda, int ldb, int ldc, float alpha, int bm, int bn) {
  __shared__ alignas(16) short Ash[4096], Asl[4096], Bsh[4096], Bsl[4096];
  const int tid = threadIdx.x;
  const int lane = tid & 63, w = tid >> 6;
  const int c = lane & 15, g = lane >> 4;
  const int wm = w >> 1, wn = w & 1;
  const int sr = lane >> 3;
  const int scs = ((lane & 7) ^ sr) * 8;

  f32x4 acc[2][2] = {};
  for (int k0 = 0; k0 < K; k0 += 64) {
    glds16(Ah + (size_t)(bm + w * 8 + sr) * lda + k0 + scs,      Ash + w * 512);
    glds16(Ah + (size_t)(bm + 32 + w * 8 + sr) * lda + k0 + scs, Ash + 2048 + w * 512);
    glds16(Bh + (size_t)(bn + w * 8 + sr) * ldb + k0 + scs,      Bsh + w * 512);
    glds16(Bh + (size_t)(bn + 32 + w * 8 + sr) * ldb + k0 + scs, Bsh + 2048 + w * 512);
    if constexpr (NPROD == 3) {
      glds16(Al + (size_t)(bm + w * 8 + sr) * lda + k0 + scs,      Asl + w * 512);
      glds16(Al + (size_t)(bm + 32 + w * 8 + sr) * lda + k0 + scs, Asl + 2048 + w * 512);
      glds16(Bl + (size_t)(bn + w * 8 + sr) * ldb + k0 + scs,      Bsl + w * 512);
      glds16(Bl + (size_t)(bn + 32 + w * 8 + sr) * ldb + k0 + scs, Bsl + 2048 + w * 512);
    }
    __syncthreads();
#pragma unroll
    for (int kk = 0; kk < 2; ++kk) {
      bf16x8 ah[2], bh[2], al[2], bl[2];
#pragma unroll
      for (int mt = 0; mt < 2; ++mt) {
        int row = wm * 32 + mt * 16 + c;
        int so = row * 64 + (((kk * 4 + g) ^ (row & 7)) * 8);
        ah[mt] = *(const bf16x8*)(Ash + so);
        if constexpr (NPROD == 3) al[mt] = *(const bf16x8*)(Asl + so);
      }
#pragma unroll
      for (int nt = 0; nt < 2; ++nt) {
        int row = wn * 32 + nt * 16 + c;
        int so = row * 64 + (((kk * 4 + g) ^ (row & 7)) * 8);
        bh[nt] = *(const bf16x8*)(Bsh + so);
        if constexpr (NPROD == 3) bl[nt] = *(const bf16x8*)(Bsl + so);
      }
#pragma unroll
      for (int mt = 0; mt < 2; ++mt)
#pragma unroll
        for (int nt = 0; nt < 2; ++nt) {
          acc[mt][nt] = __builtin_amdgcn_mfma_f32_16x16x32_bf16(ah[mt], bh[nt], acc[mt][nt], 0, 0, 0);
          if constexpr (NPROD == 3) {
            acc[mt][nt] = __builtin_amdgcn_mfma_f32_16x16x32_bf16(ah[mt], bl[nt], acc[mt][nt], 0, 0, 0);
            acc[mt][nt] = __builtin_amdgcn_mfma_f32_16x16x32_bf16(al[mt], bh[nt], acc[mt][nt], 0, 0, 0);
          }
        }
    }
    __syncthreads();
  }
#pragma unroll
  for (int mt = 0; mt < 2; ++mt) {
#pragma unroll
    for (int nt = 0; nt < 2; ++nt) {
#pragma unroll
      for (int r = 0; r < 4; ++r) {
        int m = bm + wm * 32 + mt * 16 + g * 4 + r;   // row (token)
        int n = bn + wn * 32 + nt * 16 + c;           // col (dh / N)
        float val = acc[mt][nt][r] * alpha;
        if constexpr (MODE == 0) {
          bfpair pr = split2(val);
          Ch[(size_t)m * ldc + n] = pr.hi;
          Cl[(size_t)m * ldc + n] = pr.lo;
        } else if constexpr (MODE == 3) {
          Cf[(size_t)m * ldc + n] = val;
        } else if constexpr (MODE == 4) {
          size_t off = (((size_t)(m >> 5) * 4 + (n >> 4)) * 64 +
                        ((m & 31) + 32 * ((n >> 3) & 1))) * 8 + (n & 7);
          bfpair pr = split2(val);
          Ch[off] = pr.hi;
          Cl[off] = pr.lo;
        } else {  // MODE 5
          size_t off = ((((size_t)(m >> 5) * 2 + (n >> 5)) * 2 + ((m >> 4) & 1)) * 64 +
                        ((n & 31) + 32 * ((m >> 3) & 1))) * 8 + (m & 7);
          Ch[off] = f2bf(val);
        }
      }
    }
  }
}

template <int NPROD, int MODE>
__global__ __launch_bounds__(256) void gemm3(
    const short* __restrict__ Ah, const short* __restrict__ Al,
    const short* __restrict__ Bh, const short* __restrict__ Bl,
    short* __restrict__ Ch, short* __restrict__ Cl, float* __restrict__ Cf,
    int K, int lda, int ldb, int ldc, float alpha) {
  gemm_body<NPROD, MODE>(Ah, Al, Bh, Bl, Ch, Cl, Cf, K, lda, ldb, ldc, alpha,
                         blockIdx.x * 64, blockIdx.y * 64);
}

// ---------------- fused K-proj (split->MODE4) + V-proj (single->MODE5) ----------------
__global__ __launch_bounds__(256) void kv_proj(
    const short* __restrict__ khi, const short* __restrict__ klo,
    const short* __restrict__ wkh, const short* __restrict__ wkl,
    const short* __restrict__ vb, const short* __restrict__ wvb,
    short* __restrict__ pkh, short* __restrict__ pkl, short* __restrict__ pv) {
  if (blockIdx.y == 0) {
    gemm_body<3, 4>(khi, klo, wkh, wkl, pkh, pkl, nullptr,
                    1024, 1024, 1024, 64, 1.0f, blockIdx.x * 64, 0);
  } else {
    gemm_body<1, 5>(vb, nullptr, wvb, nullptr, pv, nullptr, nullptr,
                    1024, 1024, 1024, 64, 1.0f, blockIdx.x * 64, 0);
  }
}

// ---------------- flash MQA attention (r19: packed, single-acc, splitKV, setprio) ----
// grid (S/128, H, B*NSPL), 256 thr = 4 waves; wave w owns 32 q-rows; kv range = S/4.
__global__ __launch_bounds__(256) void mqa_attn(
    const short* __restrict__ qph, const short* __restrict__ qpl,
    const short* __restrict__ pkh, const short* __restrict__ pkl,
    const short* __restrict__ pv, short* __restrict__ pO, float* __restrict__ pML) {
  const int tid = threadIdx.x;
  const int lane = tid & 63, w = tid >> 6;
  const int j = lane & 31, b5 = lane >> 5;
  const int qt = blockIdx.x, h = blockIdx.y;
  const int b = blockIdx.z >> 2, sp = blockIdx.z & 3;
  const int q0 = qt * 128 + w * 32;
  const int kvbeg = sp * (S_ / NSPL), kvend = kvbeg + S_ / NSPL;

  const size_t qbase = (size_t)(b * S_ + q0 + j) * D_ + h * DH_ + b5 * 8;
  bf16x8 qh[4], ql[4];
#pragma unroll
  for (int m = 0; m < 4; ++m) {
    qh[m] = *(const bf16x8*)(qph + qbase + m * 16);
    ql[m] = *(const bf16x8*)(qpl + qbase + m * 16);
  }

  float mrow = -1.0e30f, lrow = 0.f;
  f32x16 o0 = {}, o1 = {};

  for (int kv0 = kvbeg; kv0 < kvend; kv0 += 32) {
    const size_t tg = (size_t)((b * S_ + kv0) >> 5);
    const short* kb = pkh + tg * 2048 + lane * 8;
    const short* kb2 = pkl + tg * 2048 + lane * 8;
    bf16x8 kh[4], kl[4];
#pragma unroll
    for (int m = 0; m < 4; ++m) {
      kh[m] = *(const bf16x8*)(kb + m * 512);
      kl[m] = *(const bf16x8*)(kb2 + m * 512);
    }
    // ---- scores: 12 MFMAs chained into ONE accumulator (setprio cluster) ----
    f32x16 s = {};
    __builtin_amdgcn_s_setprio(1);
#pragma unroll
    for (int m = 0; m < 4; ++m)
      s = __builtin_amdgcn_mfma_f32_32x32x16_bf16(kh[m], qh[m], s, 0, 0, 0);
#pragma unroll
    for (int m = 0; m < 4; ++m)
      s = __builtin_amdgcn_mfma_f32_32x32x16_bf16(kl[m], qh[m], s, 0, 0, 0);
#pragma unroll
    for (int m = 0; m < 4; ++m)
      s = __builtin_amdgcn_mfma_f32_32x32x16_bf16(kh[m], ql[m], s, 0, 0, 0);
    __builtin_amdgcn_s_setprio(0);
    // ---- in-register online softmax with defer-max (THR = 8, log2 domain) ----
    float mx = s[0];
#pragma unroll
    for (int r = 1; r < 16; ++r) mx = fmaxf(mx, s[r]);
    mx = fmaxf(mx, __shfl_xor(mx, 32));
    if (!__all(mx - mrow <= 8.0f)) {
      float mn = fmaxf(mrow, mx);
      float scale = exp2f(mrow - mn);
      mrow = mn;
      lrow *= scale;
      o0 *= scale;
      o1 *= scale;
    }
    float p[16];
#pragma unroll
    for (int r = 0; r < 16; ++r) p[r] = exp2f(s[r] - mrow);
    float rs = (((p[0] + p[1]) + (p[2] + p[3])) + ((p[4] + p[5]) + (p[6] + p[7]))) +
               (((p[8] + p[9]) + (p[10] + p[11])) + ((p[12] + p[13]) + (p[14] + p[15])));
    rs += __shfl_xor(rs, 32);
    lrow += rs;
    // ---- P^T fragments via cvt_pk + permlane32_swap ----
    auto r0 = __builtin_amdgcn_permlane32_swap(cvtpk(p[0], p[1]),   cvtpk(p[4], p[5]),   false, false);
    auto r1 = __builtin_amdgcn_permlane32_swap(cvtpk(p[2], p[3]),   cvtpk(p[6], p[7]),   false, false);
    auto r2 = __builtin_amdgcn_permlane32_swap(cvtpk(p[8], p[9]),   cvtpk(p[12], p[13]), false, false);
    auto r3 = __builtin_amdgcn_permlane32_swap(cvtpk(p[10], p[11]), cvtpk(p[14], p[15]), false, false);
    union { uint4v u; bf16x8 v; } pa0, pa1;
    pa0.u = (uint4v){r0[0], r1[0], r0[1], r1[1]};  // kv 0..15 (per b5 half)
    pa1.u = (uint4v){r2[0], r3[0], r2[1], r3[1]};  // kv 16..31
    // ---- O^T += V^T x P^T (setprio cluster) ----
    const short* vbp = pv + tg * 2048 + lane * 8;
    bf16x8 va00 = *(const bf16x8*)(vbp);
    bf16x8 va01 = *(const bf16x8*)(vbp + 512);
    bf16x8 va10 = *(const bf16x8*)(vbp + 1024);
    bf16x8 va11 = *(const bf16x8*)(vbp + 1536);
    __builtin_amdgcn_s_setprio(1);
    o0 = __builtin_amdgcn_mfma_f32_32x32x16_bf16(va00, pa0.v, o0, 0, 0, 0);
    o0 = __builtin_amdgcn_mfma_f32_32x32x16_bf16(va01, pa1.v, o0, 0, 0, 0);
    o1 = __builtin_amdgcn_mfma_f32_32x32x16_bf16(va10, pa0.v, o1, 0, 0, 0);
    o1 = __builtin_amdgcn_mfma_f32_32x32x16_bf16(va11, pa1.v, o1, 0, 0, 0);
    __builtin_amdgcn_s_setprio(0);
  }
  const size_t tok = (size_t)(b * S_ + q0 + j);
  const size_t obase = ((size_t)sp * MTOT + tok) * D_ + h * DH_;
#pragma unroll
  for (int r = 0; r < 16; ++r) {
    int dh0 = (r & 3) + 8 * (r >> 2) + 4 * b5;
    pO[obase + dh0] = f2bf(o0[r]);
    pO[obase + 32 + dh0] = f2bf(o1[r]);
  }
  if (b5 == 0) {
    size_t mb = (((size_t)sp * MTOT + tok) * H_ + h) * 2;
    pML[mb] = mrow;
    pML[mb + 1] = lrow;
  }
}

// ---------------- merge NSPL KV-split partials -> single bf16 ao ----------------
__global__ __launch_bounds__(256) void attn_merge(
    const short* __restrict__ pO, const float* __restrict__ pML,
    short* __restrict__ ao) {
  int qd = blockIdx.x * 256 + threadIdx.x;
  size_t idx = (size_t)qd * 4;
  int tok = (int)(idx >> 10);
  int h = (int)((idx >> 6) & 15);
  float ms[NSPL], ls[NSPL], mm = -1.0e30f;
#pragma unroll
  for (int s = 0; s < NSPL; ++s) {
    size_t mb = (((size_t)s * MTOT + tok) * H_ + h) * 2;
    ms[s] = pML[mb];
    ls[s] = pML[mb + 1];
    mm = fmaxf(mm, ms[s]);
  }
  float num[4] = {}, den = 0.f;
#pragma unroll
  for (int s = 0; s < NSPL; ++s) {
    float e = exp2f(ms[s] - mm);
    den += ls[s] * e;
    short4v o4 = *(const short4v*)(pO + (size_t)s * MTOT * D_ + idx);
    num[0] += bf2f(o4.x) * e;
    num[1] += bf2f(o4.y) * e;
    num[2] += bf2f(o4.z) * e;
    num[3] += bf2f(o4.w) * e;
  }
  float inv = 1.0f / den;
  short4v y;
  y.x = f2bf(num[0] * inv);
  y.y = f2bf(num[1] * inv);
  y.z = f2bf(num[2] * inv);
  y.w = f2bf(num[3] * inv);
  *(short4v*)(ao + idx) = y;
}

// ---------------- launch ----------------
extern "C" void kernel_launch(void* const* d_in, const int* in_sizes, int n_in,
                              void* d_out, int out_size, void* d_ws, size_t ws_size,
                              hipStream_t stream) {
  const float* q  = (const float*)d_in[0];
  const float* k  = (const float*)d_in[1];
  const float* v  = (const float*)d_in[2];
  const float* wq = (const float*)d_in[3];
  const float* wk = (const float*)d_in[4];
  const float* wv = (const float*)d_in[5];
  const float* wo = (const float*)d_in[6];

  short* p = (short*)d_ws;
  short* qhi = p; p += 4194304;   // dead after Q-proj -> pO splits 0,1
  short* qlo = p; p += 4194304;
  short* khi = p; p += 4194304;   // dead after K-proj -> pO splits 2,3
  short* klo = p; p += 4194304;
  short* vb  = p; p += 4194304;   // dead after V-proj -> pML
  short* wqh = p; p += 1048576;
  short* wql = p; p += 1048576;
  short* wkh = p; p += 65536;
  short* wkl = p; p += 65536;
  short* wvb = p; p += 65536;
  short* wob = p; p += 1048576;
  short* qph = p; p += 4194304;   // dead after attn -> ao
  short* qpl = p; p += 4194304;
  short* pkh = p; p += 524288;    // packed K hi [128 tiles][4][64][8]
  short* pkl = p; p += 524288;    // packed K lo
  short* pv  = p; p += 524288;    // packed V^T [128 tiles][2][2][64][8]
  short* pO  = qhi;               // [NSPL][4096][1024] bf16 = 33.6 MB
  float* pML = (float*)vb;        // [NSPL][4096][16][2] f32 = 2 MB
  short* ao  = qph;               // merge runs after attn reads qph/qpl

  cvt_split<<<dim3(2048), dim3(256), 0, stream>>>(q, k, v, wq, wk, wv, wo,
      qhi, qlo, khi, klo, vb, wqh, wql, wkh, wkl, wvb, wob);
  // qp = q @ wq^T * (0.125 * log2e)  -> exp2-domain scores
  gemm3<3, 0><<<dim3(64, 16), dim3(256), 0, stream>>>(qhi, qlo, wqh, wql, qph, qpl,
      nullptr, 1024, 1024, 1024, 1024, 0.125f * 1.44269504f);
  // fused: kp -> packed split (y=0) and vp -> packed V^T (y=1)
  kv_proj<<<dim3(64, 2), dim3(256), 0, stream>>>(khi, klo, wkh, wkl, vb, wvb,
      pkh, pkl, pv);
  mqa_attn<<<dim3(S_ / 128, 16, B_ * NSPL), dim3(256), 0, stream>>>(
      qph, qpl, pkh, pkl, pv, pO, pML);
  attn_merge<<<dim3(MTOT * D_ / 4 / 256), dim3(256), 0, stream>>>(pO, pML, ao);
  // d_out(f32) = ao @ wo^T  (single bf16 — post-softmax path tolerates it)
  gemm3<1, 3><<<dim3(64, 16), dim3(256), 0, stream>>>(ao, nullptr, wob, nullptr,
      nullptr, nullptr, (float*)d_out, 1024, 1024, 1024, 1024, 1.0f);
}

// Round 22
// 190.877 us; speedup vs baseline: 1.2730x; 1.0079x over previous
//
#include <hip/hip_runtime.h>
#include <hip/hip_bf16.h>
#include <stdint.h>

// MQA: B=2, S=2048, D=1024, H=16, DH=64. Inputs f32, OUTPUT f32.
// r22: exact r20 restore (best green: 192.4us, absmax 64). r21's 2-product QK
// failed (2188>311): K storage rounding is systematic per-column -> correlated
// near-tie flips; the 3-product split is REQUIRED. This config = accumulated
// surviving wins; all other axes A/B-refuted on HW (see round notes r7-r21).

#define B_   2
#define S_   2048
#define D_   1024
#define H_   16
#define DH_  64
#define MTOT (B_ * S_)  // 4096
#define NSPL 4

typedef short bf16x8 __attribute__((ext_vector_type(8)));
typedef float f32x4 __attribute__((ext_vector_type(4)));
typedef float f32x16 __attribute__((ext_vector_type(16)));
typedef short short4v __attribute__((ext_vector_type(4)));
typedef unsigned uint4v __attribute__((ext_vector_type(4)));

__device__ __forceinline__ short f2bf(float f) {  // RNE f32->bf16
  unsigned u = __float_as_uint(f);
  u += 0x7FFF + ((u >> 16) & 1);
  return (short)(u >> 16);
}
__device__ __forceinline__ float bf2f(short h) {
  return __uint_as_float(((unsigned)(unsigned short)h) << 16);
}
struct bfpair { short hi, lo; };
__device__ __forceinline__ bfpair split2(float x) {
  bfpair p;
  p.hi = f2bf(x);
  p.lo = f2bf(x - bf2f(p.hi));
  return p;
}
__device__ __forceinline__ unsigned cvtpk(float lo, float hi) {
  unsigned r;
  asm("v_cvt_pk_bf16_f32 %0, %1, %2" : "=v"(r) : "v"(lo), "v"(hi));
  return r;
}

__device__ __forceinline__ void glds16(const void* g, void* l) {
  __builtin_amdgcn_global_load_lds((const __attribute__((address_space(1))) void*)g,
                                   (__attribute__((address_space(3))) void*)l, 16, 0, 0);
}

// ---------------- f32 -> bf16 convert; hi/lo split for q,k,wq,wk only ----------------
__global__ __launch_bounds__(256) void cvt_split(
    const float* __restrict__ q, const float* __restrict__ k, const float* __restrict__ v,
    const float* __restrict__ wq, const float* __restrict__ wk, const float* __restrict__ wv,
    const float* __restrict__ wo,
    short* qhi, short* qlo, short* khi, short* klo, short* vb,
    short* wqh, short* wql, short* wkh, short* wkl, short* wvb, short* wob) {
  const int U0 = 1048576, U1 = 2097152, U2 = 3145728, U3 = 3407872,
            U4 = 3424256, U5 = 3440640, U6 = 3702784;
  for (int u = blockIdx.x * blockDim.x + threadIdx.x; u < U6; u += gridDim.x * blockDim.x) {
    const float* s; short* dh; short* dl; int r;
    if (u < U0)      { s = q;  dh = qhi; dl = qlo; r = u; }
    else if (u < U1) { s = k;  dh = khi; dl = klo; r = u - U0; }
    else if (u < U2) { s = v;  dh = vb;  dl = nullptr; r = u - U1; }
    else if (u < U3) { s = wq; dh = wqh; dl = wql; r = u - U2; }
    else if (u < U4) { s = wk; dh = wkh; dl = wkl; r = u - U3; }
    else if (u < U5) { s = wv; dh = wvb; dl = nullptr; r = u - U4; }
    else             { s = wo; dh = wob; dl = nullptr; r = u - U5; }
    float4 x = *(const float4*)(s + (size_t)r * 4);
    bfpair p0 = split2(x.x), p1 = split2(x.y), p2 = split2(x.z), p3 = split2(x.w);
    short4v yh, yl;
    yh.x = p0.hi; yh.y = p1.hi; yh.z = p2.hi; yh.w = p3.hi;
    yl.x = p0.lo; yl.y = p1.lo; yl.z = p2.lo; yl.w = p3.lo;
    *(short4v*)(dh + (size_t)r * 4) = yh;
    if (dl) *(short4v*)(dl + (size_t)r * 4) = yl;
  }
}

// ---------------- GEMM body (device fn)  C = (Ah+Al) * (Bh+Bl)^T, f32 acc ----------
// MODE 0: split pair row-major. MODE 3: f32 row-major.
// MODE 4: K-fragment-packed split pair  PK[tok>>5][dh>>4][(tok&31)+32*((dh>>3)&1)][dh&7]
// MODE 5: V-fragment-packed single bf16 PV[tok>>5][dh>>5][(tok>>4)&1][(dh&31)+32*((tok>>3)&1)][tok&7]
template <int NPROD, int MODE>
__device__ __forceinline__ void gemm_body(
    const short* __restrict__ Ah, const short* __restrict__ Al,
    const short* __restrict__ Bh, const short* __restrict__ Bl,
    short* __restrict__ Ch, short* __restrict__ Cl, float* __restrict__ Cf,
    int K, int lda, int ldb, int ldc, float alpha, int bm, int bn) {
  __shared__ alignas(16) short Ash[4096], Asl[4096], Bsh[4096], Bsl[4096];
  const int tid = threadIdx.x;
  const int lane = tid & 63, w = tid >> 6;
  const int c = lane & 15, g = lane >> 4;
  const int wm = w >> 1, wn = w & 1;
  const int sr = lane >> 3;
  const int scs = ((lane & 7) ^ sr) * 8;

  f32x4 acc[2][2] = {};
  for (int k0 = 0; k0 < K; k0 += 64) {
    glds16(Ah + (size_t)(bm + w * 8 + sr) * lda + k0 + scs,      Ash + w * 512);
    glds16(Ah + (size_t)(bm + 32 + w * 8 + sr) * lda + k0 + scs, Ash + 2048 + w * 512);
    glds16(Bh + (size_t)(bn + w * 8 + sr) * ldb + k0 + scs,      Bsh + w * 512);
    glds16(Bh + (size_t)(bn + 32 + w * 8 + sr) * ldb + k0 + scs, Bsh + 2048 + w * 512);
    if constexpr (NPROD == 3) {
      glds16(Al + (size_t)(bm + w * 8 + sr) * lda + k0 + scs,      Asl + w * 512);
      glds16(Al + (size_t)(bm + 32 + w * 8 + sr) * lda + k0 + scs, Asl + 2048 + w * 512);
      glds16(Bl + (size_t)(bn + w * 8 + sr) * ldb + k0 + scs,      Bsl + w * 512);
      glds16(Bl + (size_t)(bn + 32 + w * 8 + sr) * ldb + k0 + scs, Bsl + 2048 + w * 512);
    }
    __syncthreads();
#pragma unroll
    for (int kk = 0; kk < 2; ++kk) {
      bf16x8 ah[2], bh[2], al[2], bl[2];
#pragma unroll
      for (int mt = 0; mt < 2; ++mt) {
        int row = wm * 32 + mt * 16 + c;
        int so = row * 64 + (((kk * 4 + g) ^ (row & 7)) * 8);
        ah[mt] = *(const bf16x8*)(Ash + so);
        if constexpr (NPROD == 3) al[mt] = *(const bf16x8*)(Asl + so);
      }
#pragma unroll
      for (int nt = 0; nt < 2; ++nt) {
        int row = wn * 32 + nt * 16 + c;
        int so = row * 64 + (((kk * 4 + g) ^ (row & 7)) * 8);
        bh[nt] = *(const bf16x8*)(Bsh + so);
        if constexpr (NPROD == 3) bl[nt] = *(const bf16x8*)(Bsl + so);
      }
#pragma unroll
      for (int mt = 0; mt < 2; ++mt)
#pragma unroll
        for (int nt = 0; nt < 2; ++nt) {
          acc[mt][nt] = __builtin_amdgcn_mfma_f32_16x16x32_bf16(ah[mt], bh[nt], acc[mt][nt], 0, 0, 0);
          if constexpr (NPROD == 3) {
            acc[mt][nt] = __builtin_amdgcn_mfma_f32_16x16x32_bf16(ah[mt], bl[nt], acc[mt][nt], 0, 0, 0);
            acc[mt][nt] = __builtin_amdgcn_mfma_f32_16x16x32_bf16(al[mt], bh[nt], acc[mt][nt], 0, 0, 0);
          }
        }
    }
    __syncthreads();
  }
#pragma unroll
  for (int mt = 0; mt < 2; ++mt) {
#pragma unroll
    for (int nt = 0; nt < 2; ++nt) {
#pragma unroll
      for (int r = 0; r < 4; ++r) {
        int m = bm + wm * 32 + mt * 16 + g * 4 + r;   // row (token)
        int n = bn + wn * 32 + nt * 16 + c;           // col (dh / N)
        float val = acc[mt][nt][r] * alpha;
        if constexpr (MODE == 0) {
          bfpair pr = split2(val);
          Ch[(size_t)m * ldc + n] = pr.hi;
          Cl[(size_t)m * ldc + n] = pr.lo;
        } else if constexpr (MODE == 3) {
          Cf[(size_t)m * ldc + n] = val;
        } else if constexpr (MODE == 4) {
          size_t off = (((size_t)(m >> 5) * 4 + (n >> 4)) * 64 +
                        ((m & 31) + 32 * ((n >> 3) & 1))) * 8 + (n & 7);
          bfpair pr = split2(val);
          Ch[off] = pr.hi;
          Cl[off] = pr.lo;
        } else {  // MODE 5
          size_t off = ((((size_t)(m >> 5) * 2 + (n >> 5)) * 2 + ((m >> 4) & 1)) * 64 +
                        ((n & 31) + 32 * ((m >> 3) & 1))) * 8 + (m & 7);
          Ch[off] = f2bf(val);
        }
      }
    }
  }
}

template <int NPROD, int MODE>
__global__ __launch_bounds__(256) void gemm3(
    const short* __restrict__ Ah, const short* __restrict__ Al,
    const short* __restrict__ Bh, const short* __restrict__ Bl,
    short* __restrict__ Ch, short* __restrict__ Cl, float* __restrict__ Cf,
    int K, int lda, int ldb, int ldc, float alpha) {
  gemm_body<NPROD, MODE>(Ah, Al, Bh, Bl, Ch, Cl, Cf, K, lda, ldb, ldc, alpha,
                         blockIdx.x * 64, blockIdx.y * 64);
}

// ---------------- fused K-proj (split->MODE4) + V-proj (single->MODE5) ----------------
__global__ __launch_bounds__(256) void kv_proj(
    const short* __restrict__ khi, const short* __restrict__ klo,
    const short* __restrict__ wkh, const short* __restrict__ wkl,
    const short* __restrict__ vb, const short* __restrict__ wvb,
    short* __restrict__ pkh, short* __restrict__ pkl, short* __restrict__ pv) {
  if (blockIdx.y == 0) {
    gemm_body<3, 4>(khi, klo, wkh, wkl, pkh, pkl, nullptr,
                    1024, 1024, 1024, 64, 1.0f, blockIdx.x * 64, 0);
  } else {
    gemm_body<1, 5>(vb, nullptr, wvb, nullptr, pv, nullptr, nullptr,
                    1024, 1024, 1024, 64, 1.0f, blockIdx.x * 64, 0);
  }
}

// ---------------- flash MQA attention (packed, single-acc, splitKV, setprio) ----
// grid (S/128, H, B*NSPL), 256 thr = 4 waves; wave w owns 32 q-rows; kv range = S/4.
__global__ __launch_bounds__(256) void mqa_attn(
    const short* __restrict__ qph, const short* __restrict__ qpl,
    const short* __restrict__ pkh, const short* __restrict__ pkl,
    const short* __restrict__ pv, short* __restrict__ pO, float* __restrict__ pML) {
  const int tid = threadIdx.x;
  const int lane = tid & 63, w = tid >> 6;
  const int j = lane & 31, b5 = lane >> 5;
  const int qt = blockIdx.x, h = blockIdx.y;
  const int b = blockIdx.z >> 2, sp = blockIdx.z & 3;
  const int q0 = qt * 128 + w * 32;
  const int kvbeg = sp * (S_ / NSPL), kvend = kvbeg + S_ / NSPL;

  const size_t qbase = (size_t)(b * S_ + q0 + j) * D_ + h * DH_ + b5 * 8;
  bf16x8 qh[4], ql[4];
#pragma unroll
  for (int m = 0; m < 4; ++m) {
    qh[m] = *(const bf16x8*)(qph + qbase + m * 16);
    ql[m] = *(const bf16x8*)(qpl + qbase + m * 16);
  }

  float mrow = -1.0e30f, lrow = 0.f;
  f32x16 o0 = {}, o1 = {};

  for (int kv0 = kvbeg; kv0 < kvend; kv0 += 32) {
    const size_t tg = (size_t)((b * S_ + kv0) >> 5);
    const short* kb = pkh + tg * 2048 + lane * 8;
    const short* kb2 = pkl + tg * 2048 + lane * 8;
    bf16x8 kh[4], kl[4];
#pragma unroll
    for (int m = 0; m < 4; ++m) {
      kh[m] = *(const bf16x8*)(kb + m * 512);
      kl[m] = *(const bf16x8*)(kb2 + m * 512);
    }
    // ---- scores: 12 MFMAs chained into ONE accumulator (setprio cluster) ----
    f32x16 s = {};
    __builtin_amdgcn_s_setprio(1);
#pragma unroll
    for (int m = 0; m < 4; ++m)
      s = __builtin_amdgcn_mfma_f32_32x32x16_bf16(kh[m], qh[m], s, 0, 0, 0);
#pragma unroll
    for (int m = 0; m < 4; ++m)
      s = __builtin_amdgcn_mfma_f32_32x32x16_bf16(kl[m], qh[m], s, 0, 0, 0);
#pragma unroll
    for (int m = 0; m < 4; ++m)
      s = __builtin_amdgcn_mfma_f32_32x32x16_bf16(kh[m], ql[m], s, 0, 0, 0);
    __builtin_amdgcn_s_setprio(0);
    // ---- in-register online softmax with defer-max (THR = 8, log2 domain) ----
    float mx = s[0];
#pragma unroll
    for (int r = 1; r < 16; ++r) mx = fmaxf(mx, s[r]);
    mx = fmaxf(mx, __shfl_xor(mx, 32));
    if (!__all(mx - mrow <= 8.0f)) {
      float mn = fmaxf(mrow, mx);
      float scale = exp2f(mrow - mn);
      mrow = mn;
      lrow *= scale;
      o0 *= scale;
      o1 *= scale;
    }
    float p[16];
#pragma unroll
    for (int r = 0; r < 16; ++r) p[r] = exp2f(s[r] - mrow);
    float rs = (((p[0] + p[1]) + (p[2] + p[3])) + ((p[4] + p[5]) + (p[6] + p[7]))) +
               (((p[8] + p[9]) + (p[10] + p[11])) + ((p[12] + p[13]) + (p[14] + p[15])));
    rs += __shfl_xor(rs, 32);
    lrow += rs;
    // ---- P^T fragments via cvt_pk + permlane32_swap ----
    auto r0 = __builtin_amdgcn_permlane32_swap(cvtpk(p[0], p[1]),   cvtpk(p[4], p[5]),   false, false);
    auto r1 = __builtin_amdgcn_permlane32_swap(cvtpk(p[2], p[3]),   cvtpk(p[6], p[7]),   false, false);
    auto r2 = __builtin_amdgcn_permlane32_swap(cvtpk(p[8], p[9]),   cvtpk(p[12], p[13]), false, false);
    auto r3 = __builtin_amdgcn_permlane32_swap(cvtpk(p[10], p[11]), cvtpk(p[14], p[15]), false, false);
    union { uint4v u; bf16x8 v; } pa0, pa1;
    pa0.u = (uint4v){r0[0], r1[0], r0[1], r1[1]};  // kv 0..15 (per b5 half)
    pa1.u = (uint4v){r2[0], r3[0], r2[1], r3[1]};  // kv 16..31
    // ---- O^T += V^T x P^T (setprio cluster) ----
    const short* vbp = pv + tg * 2048 + lane * 8;
    bf16x8 va00 = *(const bf16x8*)(vbp);
    bf16x8 va01 = *(const bf16x8*)(vbp + 512);
    bf16x8 va10 = *(const bf16x8*)(vbp + 1024);
    bf16x8 va11 = *(const bf16x8*)(vbp + 1536);
    __builtin_amdgcn_s_setprio(1);
    o0 = __builtin_amdgcn_mfma_f32_32x32x16_bf16(va00, pa0.v, o0, 0, 0, 0);
    o0 = __builtin_amdgcn_mfma_f32_32x32x16_bf16(va01, pa1.v, o0, 0, 0, 0);
    o1 = __builtin_amdgcn_mfma_f32_32x32x16_bf16(va10, pa0.v, o1, 0, 0, 0);
    o1 = __builtin_amdgcn_mfma_f32_32x32x16_bf16(va11, pa1.v, o1, 0, 0, 0);
    __builtin_amdgcn_s_setprio(0);
  }
  const size_t tok = (size_t)(b * S_ + q0 + j);
  const size_t obase = ((size_t)sp * MTOT + tok) * D_ + h * DH_;
#pragma unroll
  for (int r = 0; r < 16; ++r) {
    int dh0 = (r & 3) + 8 * (r >> 2) + 4 * b5;
    pO[obase + dh0] = f2bf(o0[r]);
    pO[obase + 32 + dh0] = f2bf(o1[r]);
  }
  if (b5 == 0) {
    size_t mb = (((size_t)sp * MTOT + tok) * H_ + h) * 2;
    pML[mb] = mrow;
    pML[mb + 1] = lrow;
  }
}

// ---------------- merge NSPL KV-split partials -> single bf16 ao ----------------
__global__ __launch_bounds__(256) void attn_merge(
    const short* __restrict__ pO, const float* __restrict__ pML,
    short* __restrict__ ao) {
  int qd = blockIdx.x * 256 + threadIdx.x;
  size_t idx = (size_t)qd * 4;
  int tok = (int)(idx >> 10);
  int h = (int)((idx >> 6) & 15);
  float ms[NSPL], ls[NSPL], mm = -1.0e30f;
#pragma unroll
  for (int s = 0; s < NSPL; ++s) {
    size_t mb = (((size_t)s * MTOT + tok) * H_ + h) * 2;
    ms[s] = pML[mb];
    ls[s] = pML[mb + 1];
    mm = fmaxf(mm, ms[s]);
  }
  float num[4] = {}, den = 0.f;
#pragma unroll
  for (int s = 0; s < NSPL; ++s) {
    float e = exp2f(ms[s] - mm);
    den += ls[s] * e;
    short4v o4 = *(const short4v*)(pO + (size_t)s * MTOT * D_ + idx);
    num[0] += bf2f(o4.x) * e;
    num[1] += bf2f(o4.y) * e;
    num[2] += bf2f(o4.z) * e;
    num[3] += bf2f(o4.w) * e;
  }
  float inv = 1.0f / den;
  short4v y;
  y.x = f2bf(num[0] * inv);
  y.y = f2bf(num[1] * inv);
  y.z = f2bf(num[2] * inv);
  y.w = f2bf(num[3] * inv);
  *(short4v*)(ao + idx) = y;
}

// ---------------- launch ----------------
extern "C" void kernel_launch(void* const* d_in, const int* in_sizes, int n_in,
                              void* d_out, int out_size, void* d_ws, size_t ws_size,
                              hipStream_t stream) {
  const float* q  = (const float*)d_in[0];
  const float* k  = (const float*)d_in[1];
  const float* v  = (const float*)d_in[2];
  const float* wq = (const float*)d_in[3];
  const float* wk = (const float*)d_in[4];
  const float* wv = (const float*)d_in[5];
  const float* wo = (const float*)d_in[6];

  short* p = (short*)d_ws;
  short* qhi = p; p += 4194304;   // dead after Q-proj -> pO splits 0,1
  short* qlo = p; p += 4194304;
  short* khi = p; p += 4194304;   // dead after K-proj -> pO splits 2,3
  short* klo = p; p += 4194304;
  short* vb  = p; p += 4194304;   // dead after V-proj -> pML
  short* wqh = p; p += 1048576;
  short* wql = p; p += 1048576;
  short* wkh = p; p += 65536;
  short* wkl = p; p += 65536;
  short* wvb = p; p += 65536;
  short* wob = p; p += 1048576;
  short* qph = p; p += 4194304;   // dead after attn -> ao
  short* qpl = p; p += 4194304;
  short* pkh = p; p += 524288;    // packed K hi [128 tiles][4][64][8]
  short* pkl = p; p += 524288;    // packed K lo
  short* pv  = p; p += 524288;    // packed V^T [128 tiles][2][2][64][8]
  short* pO  = qhi;               // [NSPL][4096][1024] bf16 = 33.6 MB
  float* pML = (float*)vb;        // [NSPL][4096][16][2] f32 = 2 MB
  short* ao  = qph;               // merge runs after attn reads qph/qpl

  cvt_split<<<dim3(2048), dim3(256), 0, stream>>>(q, k, v, wq, wk, wv, wo,
      qhi, qlo, khi, klo, vb, wqh, wql, wkh, wkl, wvb, wob);
  // qp = q @ wq^T * (0.125 * log2e)  -> exp2-domain scores
  gemm3<3, 0><<<dim3(64, 16), dim3(256), 0, stream>>>(qhi, qlo, wqh, wql, qph, qpl,
      nullptr, 1024, 1024, 1024, 1024, 0.125f * 1.44269504f);
  // fused: kp -> packed split (y=0) and vp -> packed V^T (y=1)
  kv_proj<<<dim3(64, 2), dim3(256), 0, stream>>>(khi, klo, wkh, wkl, vb, wvb,
      pkh, pkl, pv);
  mqa_attn<<<dim3(S_ / 128, 16, B_ * NSPL), dim3(256), 0, stream>>>(
      qph, qpl, pkh, pkl, pv, pO, pML);
  attn_merge<<<dim3(MTOT * D_ / 4 / 256), dim3(256), 0, stream>>>(pO, pML, ao);
  // d_out(f32) = ao @ wo^T  (single bf16 — post-softmax path tolerates it)
  gemm3<1, 3><<<dim3(64, 16), dim3(256), 0, stream>>>(ao, nullptr, wob, nullptr,
      nullptr, nullptr, (float*)d_out, 1024, 1024, 1024, 1024, 1.0f);
}

// Round 23
// 190.831 us; speedup vs baseline: 1.2733x; 1.0002x over previous
//
#include <hip/hip_runtime.h>
#include <hip/hip_bf16.h>
#include <stdint.h>

// MQA: B=2, S=2048, D=1024, H=16, DH=64. Inputs f32, OUTPUT f32.
// r23: r22 (best green: 190.9us) + ALL THREE projections fused into one
// 1152-block launch (Q-proj 1024 blocks + K-proj 64 + V-proj 64). They are
// mutually independent; the starved 128-block kv_proj now fills Q-proj's
// idle CUs instead of running serialized (r20's fusion mechanism, extended).

#define B_   2
#define S_   2048
#define D_   1024
#define H_   16
#define DH_  64
#define MTOT (B_ * S_)  // 4096
#define NSPL 4

typedef short bf16x8 __attribute__((ext_vector_type(8)));
typedef float f32x4 __attribute__((ext_vector_type(4)));
typedef float f32x16 __attribute__((ext_vector_type(16)));
typedef short short4v __attribute__((ext_vector_type(4)));
typedef unsigned uint4v __attribute__((ext_vector_type(4)));

__device__ __forceinline__ short f2bf(float f) {  // RNE f32->bf16
  unsigned u = __float_as_uint(f);
  u += 0x7FFF + ((u >> 16) & 1);
  return (short)(u >> 16);
}
__device__ __forceinline__ float bf2f(short h) {
  return __uint_as_float(((unsigned)(unsigned short)h) << 16);
}
struct bfpair { short hi, lo; };
__device__ __forceinline__ bfpair split2(float x) {
  bfpair p;
  p.hi = f2bf(x);
  p.lo = f2bf(x - bf2f(p.hi));
  return p;
}
__device__ __forceinline__ unsigned cvtpk(float lo, float hi) {
  unsigned r;
  asm("v_cvt_pk_bf16_f32 %0, %1, %2" : "=v"(r) : "v"(lo), "v"(hi));
  return r;
}

__device__ __forceinline__ void glds16(const void* g, void* l) {
  __builtin_amdgcn_global_load_lds((const __attribute__((address_space(1))) void*)g,
                                   (__attribute__((address_space(3))) void*)l, 16, 0, 0);
}

// ---------------- f32 -> bf16 convert; hi/lo split for q,k,wq,wk only ----------------
__global__ __launch_bounds__(256) void cvt_split(
    const float* __restrict__ q, const float* __restrict__ k, const float* __restrict__ v,
    const float* __restrict__ wq, const float* __restrict__ wk, const float* __restrict__ wv,
    const float* __restrict__ wo,
    short* qhi, short* qlo, short* khi, short* klo, short* vb,
    short* wqh, short* wql, short* wkh, short* wkl, short* wvb, short* wob) {
  const int U0 = 1048576, U1 = 2097152, U2 = 3145728, U3 = 3407872,
            U4 = 3424256, U5 = 3440640, U6 = 3702784;
  for (int u = blockIdx.x * blockDim.x + threadIdx.x; u < U6; u += gridDim.x * blockDim.x) {
    const float* s; short* dh; short* dl; int r;
    if (u < U0)      { s = q;  dh = qhi; dl = qlo; r = u; }
    else if (u < U1) { s = k;  dh = khi; dl = klo; r = u - U0; }
    else if (u < U2) { s = v;  dh = vb;  dl = nullptr; r = u - U1; }
    else if (u < U3) { s = wq; dh = wqh; dl = wql; r = u - U2; }
    else if (u < U4) { s = wk; dh = wkh; dl = wkl; r = u - U3; }
    else if (u < U5) { s = wv; dh = wvb; dl = nullptr; r = u - U4; }
    else             { s = wo; dh = wob; dl = nullptr; r = u - U5; }
    float4 x = *(const float4*)(s + (size_t)r * 4);
    bfpair p0 = split2(x.x), p1 = split2(x.y), p2 = split2(x.z), p3 = split2(x.w);
    short4v yh, yl;
    yh.x = p0.hi; yh.y = p1.hi; yh.z = p2.hi; yh.w = p3.hi;
    yl.x = p0.lo; yl.y = p1.lo; yl.z = p2.lo; yl.w = p3.lo;
    *(short4v*)(dh + (size_t)r * 4) = yh;
    if (dl) *(short4v*)(dl + (size_t)r * 4) = yl;
  }
}

// ---------------- GEMM body (device fn)  C = (Ah+Al) * (Bh+Bl)^T, f32 acc ----------
// MODE 0: split pair row-major. MODE 3: f32 row-major.
// MODE 4: K-fragment-packed split pair  PK[tok>>5][dh>>4][(tok&31)+32*((dh>>3)&1)][dh&7]
// MODE 5: V-fragment-packed single bf16 PV[tok>>5][dh>>5][(tok>>4)&1][(dh&31)+32*((tok>>3)&1)][tok&7]
template <int NPROD, int MODE>
__device__ __forceinline__ void gemm_body(
    const short* __restrict__ Ah, const short* __restrict__ Al,
    const short* __restrict__ Bh, const short* __restrict__ Bl,
    short* __restrict__ Ch, short* __restrict__ Cl, float* __restrict__ Cf,
    int K, int lda, int ldb, int ldc, float alpha, int bm, int bn) {
  __shared__ alignas(16) short Ash[4096], Asl[4096], Bsh[4096], Bsl[4096];
  const int tid = threadIdx.x;
  const int lane = tid & 63, w = tid >> 6;
  const int c = lane & 15, g = lane >> 4;
  const int wm = w >> 1, wn = w & 1;
  const int sr = lane >> 3;
  const int scs = ((lane & 7) ^ sr) * 8;

  f32x4 acc[2][2] = {};
  for (int k0 = 0; k0 < K; k0 += 64) {
    glds16(Ah + (size_t)(bm + w * 8 + sr) * lda + k0 + scs,      Ash + w * 512);
    glds16(Ah + (size_t)(bm + 32 + w * 8 + sr) * lda + k0 + scs, Ash + 2048 + w * 512);
    glds16(Bh + (size_t)(bn + w * 8 + sr) * ldb + k0 + scs,      Bsh + w * 512);
    glds16(Bh + (size_t)(bn + 32 + w * 8 + sr) * ldb + k0 + scs, Bsh + 2048 + w * 512);
    if constexpr (NPROD == 3) {
      glds16(Al + (size_t)(bm + w * 8 + sr) * lda + k0 + scs,      Asl + w * 512);
      glds16(Al + (size_t)(bm + 32 + w * 8 + sr) * lda + k0 + scs, Asl + 2048 + w * 512);
      glds16(Bl + (size_t)(bn + w * 8 + sr) * ldb + k0 + scs,      Bsl + w * 512);
      glds16(Bl + (size_t)(bn + 32 + w * 8 + sr) * ldb + k0 + scs, Bsl + 2048 + w * 512);
    }
    __syncthreads();
#pragma unroll
    for (int kk = 0; kk < 2; ++kk) {
      bf16x8 ah[2], bh[2], al[2], bl[2];
#pragma unroll
      for (int mt = 0; mt < 2; ++mt) {
        int row = wm * 32 + mt * 16 + c;
        int so = row * 64 + (((kk * 4 + g) ^ (row & 7)) * 8);
        ah[mt] = *(const bf16x8*)(Ash + so);
        if constexpr (NPROD == 3) al[mt] = *(const bf16x8*)(Asl + so);
      }
#pragma unroll
      for (int nt = 0; nt < 2; ++nt) {
        int row = wn * 32 + nt * 16 + c;
        int so = row * 64 + (((kk * 4 + g) ^ (row & 7)) * 8);
        bh[nt] = *(const bf16x8*)(Bsh + so);
        if constexpr (NPROD == 3) bl[nt] = *(const bf16x8*)(Bsl + so);
      }
#pragma unroll
      for (int mt = 0; mt < 2; ++mt)
#pragma unroll
        for (int nt = 0; nt < 2; ++nt) {
          acc[mt][nt] = __builtin_amdgcn_mfma_f32_16x16x32_bf16(ah[mt], bh[nt], acc[mt][nt], 0, 0, 0);
          if constexpr (NPROD == 3) {
            acc[mt][nt] = __builtin_amdgcn_mfma_f32_16x16x32_bf16(ah[mt], bl[nt], acc[mt][nt], 0, 0, 0);
            acc[mt][nt] = __builtin_amdgcn_mfma_f32_16x16x32_bf16(al[mt], bh[nt], acc[mt][nt], 0, 0, 0);
          }
        }
    }
    __syncthreads();
  }
#pragma unroll
  for (int mt = 0; mt < 2; ++mt) {
#pragma unroll
    for (int nt = 0; nt < 2; ++nt) {
#pragma unroll
      for (int r = 0; r < 4; ++r) {
        int m = bm + wm * 32 + mt * 16 + g * 4 + r;   // row (token)
        int n = bn + wn * 32 + nt * 16 + c;           // col (dh / N)
        float val = acc[mt][nt][r] * alpha;
        if constexpr (MODE == 0) {
          bfpair pr = split2(val);
          Ch[(size_t)m * ldc + n] = pr.hi;
          Cl[(size_t)m * ldc + n] = pr.lo;
        } else if constexpr (MODE == 3) {
          Cf[(size_t)m * ldc + n] = val;
        } else if constexpr (MODE == 4) {
          size_t off = (((size_t)(m >> 5) * 4 + (n >> 4)) * 64 +
                        ((m & 31) + 32 * ((n >> 3) & 1))) * 8 + (n & 7);
          bfpair pr = split2(val);
          Ch[off] = pr.hi;
          Cl[off] = pr.lo;
        } else {  // MODE 5
          size_t off = ((((size_t)(m >> 5) * 2 + (n >> 5)) * 2 + ((m >> 4) & 1)) * 64 +
                        ((n & 31) + 32 * ((m >> 3) & 1))) * 8 + (m & 7);
          Ch[off] = f2bf(val);
        }
      }
    }
  }
}

template <int NPROD, int MODE>
__global__ __launch_bounds__(256) void gemm3(
    const short* __restrict__ Ah, const short* __restrict__ Al,
    const short* __restrict__ Bh, const short* __restrict__ Bl,
    short* __restrict__ Ch, short* __restrict__ Cl, float* __restrict__ Cf,
    int K, int lda, int ldb, int ldc, float alpha) {
  gemm_body<NPROD, MODE>(Ah, Al, Bh, Bl, Ch, Cl, Cf, K, lda, ldb, ldc, alpha,
                         blockIdx.x * 64, blockIdx.y * 64);
}

// ---- fused Q-proj (split->MODE0) + K-proj (split->MODE4) + V-proj (single->MODE5) ----
// grid: 1152 blocks. [0,1024) Q-proj (bm=(i&63)*64, bn=(i>>6)*64); [1024,1088) K; [1088,1152) V.
__global__ __launch_bounds__(256) void proj_all(
    const short* __restrict__ qhi, const short* __restrict__ qlo,
    const short* __restrict__ wqh, const short* __restrict__ wql,
    const short* __restrict__ khi, const short* __restrict__ klo,
    const short* __restrict__ wkh, const short* __restrict__ wkl,
    const short* __restrict__ vb, const short* __restrict__ wvb,
    short* __restrict__ qph, short* __restrict__ qpl,
    short* __restrict__ pkh, short* __restrict__ pkl, short* __restrict__ pv,
    float alphaq) {
  const int idx = blockIdx.x;
  if (idx < 1024) {
    gemm_body<3, 0>(qhi, qlo, wqh, wql, qph, qpl, nullptr,
                    1024, 1024, 1024, 1024, alphaq, (idx & 63) * 64, (idx >> 6) * 64);
  } else if (idx < 1088) {
    gemm_body<3, 4>(khi, klo, wkh, wkl, pkh, pkl, nullptr,
                    1024, 1024, 1024, 64, 1.0f, (idx - 1024) * 64, 0);
  } else {
    gemm_body<1, 5>(vb, nullptr, wvb, nullptr, pv, nullptr, nullptr,
                    1024, 1024, 1024, 64, 1.0f, (idx - 1088) * 64, 0);
  }
}

// ---------------- flash MQA attention (packed, single-acc, splitKV, setprio) ----
// grid (S/128, H, B*NSPL), 256 thr = 4 waves; wave w owns 32 q-rows; kv range = S/4.
__global__ __launch_bounds__(256) void mqa_attn(
    const short* __restrict__ qph, const short* __restrict__ qpl,
    const short* __restrict__ pkh, const short* __restrict__ pkl,
    const short* __restrict__ pv, short* __restrict__ pO, float* __restrict__ pML) {
  const int tid = threadIdx.x;
  const int lane = tid & 63, w = tid >> 6;
  const int j = lane & 31, b5 = lane >> 5;
  const int qt = blockIdx.x, h = blockIdx.y;
  const int b = blockIdx.z >> 2, sp = blockIdx.z & 3;
  const int q0 = qt * 128 + w * 32;
  const int kvbeg = sp * (S_ / NSPL), kvend = kvbeg + S_ / NSPL;

  const size_t qbase = (size_t)(b * S_ + q0 + j) * D_ + h * DH_ + b5 * 8;
  bf16x8 qh[4], ql[4];
#pragma unroll
  for (int m = 0; m < 4; ++m) {
    qh[m] = *(const bf16x8*)(qph + qbase + m * 16);
    ql[m] = *(const bf16x8*)(qpl + qbase + m * 16);
  }

  float mrow = -1.0e30f, lrow = 0.f;
  f32x16 o0 = {}, o1 = {};

  for (int kv0 = kvbeg; kv0 < kvend; kv0 += 32) {
    const size_t tg = (size_t)((b * S_ + kv0) >> 5);
    const short* kb = pkh + tg * 2048 + lane * 8;
    const short* kb2 = pkl + tg * 2048 + lane * 8;
    bf16x8 kh[4], kl[4];
#pragma unroll
    for (int m = 0; m < 4; ++m) {
      kh[m] = *(const bf16x8*)(kb + m * 512);
      kl[m] = *(const bf16x8*)(kb2 + m * 512);
    }
    // ---- scores: 12 MFMAs chained into ONE accumulator (setprio cluster) ----
    f32x16 s = {};
    __builtin_amdgcn_s_setprio(1);
#pragma unroll
    for (int m = 0; m < 4; ++m)
      s = __builtin_amdgcn_mfma_f32_32x32x16_bf16(kh[m], qh[m], s, 0, 0, 0);
#pragma unroll
    for (int m = 0; m < 4; ++m)
      s = __builtin_amdgcn_mfma_f32_32x32x16_bf16(kl[m], qh[m], s, 0, 0, 0);
#pragma unroll
    for (int m = 0; m < 4; ++m)
      s = __builtin_amdgcn_mfma_f32_32x32x16_bf16(kh[m], ql[m], s, 0, 0, 0);
    __builtin_amdgcn_s_setprio(0);
    // ---- in-register online softmax with defer-max (THR = 8, log2 domain) ----
    float mx = s[0];
#pragma unroll
    for (int r = 1; r < 16; ++r) mx = fmaxf(mx, s[r]);
    mx = fmaxf(mx, __shfl_xor(mx, 32));
    if (!__all(mx - mrow <= 8.0f)) {
      float mn = fmaxf(mrow, mx);
      float scale = exp2f(mrow - mn);
      mrow = mn;
      lrow *= scale;
      o0 *= scale;
      o1 *= scale;
    }
    float p[16];
#pragma unroll
    for (int r = 0; r < 16; ++r) p[r] = exp2f(s[r] - mrow);
    float rs = (((p[0] + p[1]) + (p[2] + p[3])) + ((p[4] + p[5]) + (p[6] + p[7]))) +
               (((p[8] + p[9]) + (p[10] + p[11])) + ((p[12] + p[13]) + (p[14] + p[15])));
    rs += __shfl_xor(rs, 32);
    lrow += rs;
    // ---- P^T fragments via cvt_pk + permlane32_swap ----
    auto r0 = __builtin_amdgcn_permlane32_swap(cvtpk(p[0], p[1]),   cvtpk(p[4], p[5]),   false, false);
    auto r1 = __builtin_amdgcn_permlane32_swap(cvtpk(p[2], p[3]),   cvtpk(p[6], p[7]),   false, false);
    auto r2 = __builtin_amdgcn_permlane32_swap(cvtpk(p[8], p[9]),   cvtpk(p[12], p[13]), false, false);
    auto r3 = __builtin_amdgcn_permlane32_swap(cvtpk(p[10], p[11]), cvtpk(p[14], p[15]), false, false);
    union { uint4v u; bf16x8 v; } pa0, pa1;
    pa0.u = (uint4v){r0[0], r1[0], r0[1], r1[1]};  // kv 0..15 (per b5 half)
    pa1.u = (uint4v){r2[0], r3[0], r2[1], r3[1]};  // kv 16..31
    // ---- O^T += V^T x P^T (setprio cluster) ----
    const short* vbp = pv + tg * 2048 + lane * 8;
    bf16x8 va00 = *(const bf16x8*)(vbp);
    bf16x8 va01 = *(const bf16x8*)(vbp + 512);
    bf16x8 va10 = *(const bf16x8*)(vbp + 1024);
    bf16x8 va11 = *(const bf16x8*)(vbp + 1536);
    __builtin_amdgcn_s_setprio(1);
    o0 = __builtin_amdgcn_mfma_f32_32x32x16_bf16(va00, pa0.v, o0, 0, 0, 0);
    o0 = __builtin_amdgcn_mfma_f32_32x32x16_bf16(va01, pa1.v, o0, 0, 0, 0);
    o1 = __builtin_amdgcn_mfma_f32_32x32x16_bf16(va10, pa0.v, o1, 0, 0, 0);
    o1 = __builtin_amdgcn_mfma_f32_32x32x16_bf16(va11, pa1.v, o1, 0, 0, 0);
    __builtin_amdgcn_s_setprio(0);
  }
  const size_t tok = (size_t)(b * S_ + q0 + j);
  const size_t obase = ((size_t)sp * MTOT + tok) * D_ + h * DH_;
#pragma unroll
  for (int r = 0; r < 16; ++r) {
    int dh0 = (r & 3) + 8 * (r >> 2) + 4 * b5;
    pO[obase + dh0] = f2bf(o0[r]);
    pO[obase + 32 + dh0] = f2bf(o1[r]);
  }
  if (b5 == 0) {
    size_t mb = (((size_t)sp * MTOT + tok) * H_ + h) * 2;
    pML[mb] = mrow;
    pML[mb + 1] = lrow;
  }
}

// ---------------- merge NSPL KV-split partials -> single bf16 ao ----------------
__global__ __launch_bounds__(256) void attn_merge(
    const short* __restrict__ pO, const float* __restrict__ pML,
    short* __restrict__ ao) {
  int qd = blockIdx.x * 256 + threadIdx.x;
  size_t idx = (size_t)qd * 4;
  int tok = (int)(idx >> 10);
  int h = (int)((idx >> 6) & 15);
  float ms[NSPL], ls[NSPL], mm = -1.0e30f;
#pragma unroll
  for (int s = 0; s < NSPL; ++s) {
    size_t mb = (((size_t)s * MTOT + tok) * H_ + h) * 2;
    ms[s] = pML[mb];
    ls[s] = pML[mb + 1];
    mm = fmaxf(mm, ms[s]);
  }
  float num[4] = {}, den = 0.f;
#pragma unroll
  for (int s = 0; s < NSPL; ++s) {
    float e = exp2f(ms[s] - mm);
    den += ls[s] * e;
    short4v o4 = *(const short4v*)(pO + (size_t)s * MTOT * D_ + idx);
    num[0] += bf2f(o4.x) * e;
    num[1] += bf2f(o4.y) * e;
    num[2] += bf2f(o4.z) * e;
    num[3] += bf2f(o4.w) * e;
  }
  float inv = 1.0f / den;
  short4v y;
  y.x = f2bf(num[0] * inv);
  y.y = f2bf(num[1] * inv);
  y.z = f2bf(num[2] * inv);
  y.w = f2bf(num[3] * inv);
  *(short4v*)(ao + idx) = y;
}

// ---------------- launch ----------------
extern "C" void kernel_launch(void* const* d_in, const int* in_sizes, int n_in,
                              void* d_out, int out_size, void* d_ws, size_t ws_size,
                              hipStream_t stream) {
  const float* q  = (const float*)d_in[0];
  const float* k  = (const float*)d_in[1];
  const float* v  = (const float*)d_in[2];
  const float* wq = (const float*)d_in[3];
  const float* wk = (const float*)d_in[4];
  const float* wv = (const float*)d_in[5];
  const float* wo = (const float*)d_in[6];

  short* p = (short*)d_ws;
  short* qhi = p; p += 4194304;   // dead after proj_all -> pO splits 0,1
  short* qlo = p; p += 4194304;
  short* khi = p; p += 4194304;   // dead after proj_all -> pO splits 2,3
  short* klo = p; p += 4194304;
  short* vb  = p; p += 4194304;   // dead after proj_all -> pML
  short* wqh = p; p += 1048576;
  short* wql = p; p += 1048576;
  short* wkh = p; p += 65536;
  short* wkl = p; p += 65536;
  short* wvb = p; p += 65536;
  short* wob = p; p += 1048576;
  short* qph = p; p += 4194304;   // dead after attn -> ao
  short* qpl = p; p += 4194304;
  short* pkh = p; p += 524288;    // packed K hi [128 tiles][4][64][8]
  short* pkl = p; p += 524288;    // packed K lo
  short* pv  = p; p += 524288;    // packed V^T [128 tiles][2][2][64][8]
  short* pO  = qhi;               // [NSPL][4096][1024] bf16 = 33.6 MB
  float* pML = (float*)vb;        // [NSPL][4096][16][2] f32 = 2 MB
  short* ao  = qph;               // merge runs after attn reads qph/qpl

  cvt_split<<<dim3(2048), dim3(256), 0, stream>>>(q, k, v, wq, wk, wv, wo,
      qhi, qlo, khi, klo, vb, wqh, wql, wkh, wkl, wvb, wob);
  // fused projections: qp (split, exp2-domain alpha) + packed K (split) + packed V^T
  proj_all<<<dim3(1152), dim3(256), 0, stream>>>(
      qhi, qlo, wqh, wql, khi, klo, wkh, wkl, vb, wvb,
      qph, qpl, pkh, pkl, pv, 0.125f * 1.44269504f);
  mqa_attn<<<dim3(S_ / 128, 16, B_ * NSPL), dim3(256), 0, stream>>>(
      qph, qpl, pkh, pkl, pv, pO, pML);
  attn_merge<<<dim3(MTOT * D_ / 4 / 256), dim3(256), 0, stream>>>(pO, pML, ao);
  // d_out(f32) = ao @ wo^T  (single bf16 — post-softmax path tolerates it)
  gemm3<1, 3><<<dim3(64, 16), dim3(256), 0, stream>>>(ao, nullptr, wob, nullptr,
      nullptr, nullptr, (float*)d_out, 1024, 1024, 1024, 1024, 1.0f);
}